// Round 1
// baseline (4023.499 us; speedup 1.0000x reference)
//
#include <hip/hip_runtime.h>
#include <math.h>

#define NNODE 100000
#define NEDGE 800000
#define DF 128
#define EDIM 32

// ---------------- CSR build ----------------

__global__ void hist_kernel(const int* __restrict__ dst, int* __restrict__ cnt, int ne) {
  int i = blockIdx.x * blockDim.x + threadIdx.x;
  if (i < ne) atomicAdd(&cnt[dst[i]], 1);
}

// exclusive scan of cnt[0..n) -> off[0..n], single block, 1024 threads, 8 elems/thread/chunk
__global__ __launch_bounds__(1024) void scan_kernel(const int* __restrict__ cnt,
                                                    int* __restrict__ off, int n) {
  __shared__ int lds[1024];
  __shared__ int carry_s;
  int t = threadIdx.x;
  if (t == 0) carry_s = 0;
  __syncthreads();
  for (int base = 0; base < n; base += 8192) {
    int x[8];
    int s = 0;
#pragma unroll
    for (int i = 0; i < 8; ++i) {
      int idx = base + t * 8 + i;
      x[i] = (idx < n) ? cnt[idx] : 0;
      s += x[i];
    }
    lds[t] = s;
    __syncthreads();
#pragma unroll
    for (int st = 1; st < 1024; st <<= 1) {
      int v2 = (t >= st) ? lds[t - st] : 0;
      __syncthreads();
      lds[t] += v2;
      __syncthreads();
    }
    int excl = carry_s + lds[t] - s;  // exclusive prefix of this thread's chunk slice
#pragma unroll
    for (int i = 0; i < 8; ++i) {
      int idx = base + t * 8 + i;
      if (idx < n) off[idx] = excl;
      excl += x[i];
    }
    __syncthreads();
    if (t == 0) carry_s += lds[1023];
    __syncthreads();
  }
  if (t == 0) off[n] = carry_s;
}

__global__ void scatter_kernel(const int* __restrict__ dst, int* __restrict__ cursor,
                               int* __restrict__ eid, int ne) {
  int i = blockIdx.x * blockDim.x + threadIdx.x;
  if (i < ne) {
    int p = atomicAdd(&cursor[dst[i]], 1);
    eid[p] = i;
  }
}

// ---------------- node projections: Y1 = X@W1+b1, Y2 = X@W2+b2 ----------------
// X [n,128] row-major, W [128,128] row-major (D x H), Y [n,128]
// block: 256 threads, tile 64 rows x 128 cols; thread = 8 rows x 4 cols
__global__ __launch_bounds__(256) void proj2_kernel(
    const float* __restrict__ X, int n,
    const float* __restrict__ W1, const float* __restrict__ b1, float* __restrict__ Y1,
    const float* __restrict__ W2, const float* __restrict__ b2, float* __restrict__ Y2) {
  __shared__ float Xs[128][65];  // [k][r], padded to kill bank conflicts on staging writes
  int row0 = blockIdx.x * 64;
  int t = threadIdx.x;
  {
    const float4* Xv = (const float4*)(X + (size_t)row0 * DF);
#pragma unroll
    for (int i = 0; i < 8; ++i) {
      int idx = t + i * 256;  // float4 index in [0,2048)
      int r = idx >> 5;       // 32 float4 per row
      int k4 = idx & 31;
      float4 val = make_float4(0.f, 0.f, 0.f, 0.f);
      if (row0 + r < n) val = Xv[idx];
      Xs[k4 * 4 + 0][r] = val.x;
      Xs[k4 * 4 + 1][r] = val.y;
      Xs[k4 * 4 + 2][r] = val.z;
      Xs[k4 * 4 + 3][r] = val.w;
    }
  }
  __syncthreads();
  int tx = t & 31;  // cols tx*4 .. +3
  int ty = t >> 5;  // rows ty*8 .. +7

  for (int p = 0; p < 2; ++p) {
    const float* W = p ? W2 : W1;
    const float* bb = p ? b2 : b1;
    float* Y = p ? Y2 : Y1;
    float acc[8][4];
#pragma unroll
    for (int i = 0; i < 8; ++i)
#pragma unroll
      for (int j = 0; j < 4; ++j) acc[i][j] = 0.f;
#pragma unroll 4
    for (int k = 0; k < 128; ++k) {
      float4 wv = *(const float4*)(W + k * DF + tx * 4);
      float xr[8];
#pragma unroll
      for (int i = 0; i < 8; ++i) xr[i] = Xs[k][ty * 8 + i];
#pragma unroll
      for (int i = 0; i < 8; ++i) {
        acc[i][0] += xr[i] * wv.x;
        acc[i][1] += xr[i] * wv.y;
        acc[i][2] += xr[i] * wv.z;
        acc[i][3] += xr[i] * wv.w;
      }
    }
    float bv0 = bb[tx * 4 + 0], bv1 = bb[tx * 4 + 1], bv2 = bb[tx * 4 + 2], bv3 = bb[tx * 4 + 3];
#pragma unroll
    for (int i = 0; i < 8; ++i) {
      int r = row0 + ty * 8 + i;
      if (r < n) {
        float4 o = make_float4(acc[i][0] + bv0, acc[i][1] + bv1, acc[i][2] + bv2, acc[i][3] + bv3);
        *(float4*)(Y + (size_t)r * DF + tx * 4) = o;
      }
    }
  }
}

// ---------------- fused edge attention (one wave per destination node) ----------------
// online softmax over the CSR segment; ee = ea@We+be computed on the fly (We in LDS)
__global__ __launch_bounds__(256) void edge_attn_kernel(
    const float* __restrict__ q,   // [nd,128] dst projection
    const float* __restrict__ k,   // [ns,128] src key proj
    const float* __restrict__ v,   // [ns,128] src value proj
    const float* __restrict__ ea,  // [E,32]
    const float* __restrict__ We,  // [32,128]
    const float* __restrict__ be,  // [128]
    const int* __restrict__ esrc,  // [E] src node per edge
    const int* __restrict__ off,   // [nd+1]
    const int* __restrict__ eid,   // [E] edge ids sorted by dst
    float* __restrict__ out,       // [nd,128], pre-initialized with x_dst@Ws+bs
    int nd, int relu) {
  __shared__ float WeL[32][128];
  __shared__ float beL[128];
  int t = threadIdx.x;
  for (int i = t; i < 32 * 128; i += 256) WeL[i >> 7][i & 127] = We[i];
  if (t < 128) beL[t] = be[t];
  __syncthreads();

  int wave = t >> 6, lane = t & 63;
  int node = blockIdx.x * 4 + wave;
  if (node >= nd) return;

  int e0 = off[node], e1 = off[node + 1];
  float q0 = q[(size_t)node * DF + lane];
  float q1 = q[(size_t)node * DF + 64 + lane];
  float m = -INFINITY, ssum = 0.f, agg0 = 0.f, agg1 = 0.f;
  const float scale = 0.08838834764831845f;  // 128^-0.5

  for (int j = e0; j < e1; ++j) {
    int e = eid[j];
    int s = esrc[e];
    // ee = ea[e] @ We + be  (each lane: dims lane and lane+64)
    float aval = ea[(size_t)e * EDIM + (lane & 31)];
    float ee0 = beL[lane];
    float ee1 = beL[64 + lane];
#pragma unroll
    for (int jj = 0; jj < 32; ++jj) {
      float a = __shfl(aval, jj, 32);
      ee0 += a * WeL[jj][lane];
      ee1 += a * WeL[jj][64 + lane];
    }
    float k0 = k[(size_t)s * DF + lane] + ee0;
    float k1 = k[(size_t)s * DF + 64 + lane] + ee1;
    float p = q0 * k0 + q1 * k1;
#pragma unroll
    for (int o = 32; o > 0; o >>= 1) p += __shfl_xor(p, o);
    float alpha = p * scale;
    if (alpha > m) {  // wave-uniform branch
      float f = __expf(m - alpha);
      ssum *= f;
      agg0 *= f;
      agg1 *= f;
      m = alpha;
    }
    float w = __expf(alpha - m);
    ssum += w;
    float v0 = v[(size_t)s * DF + lane] + ee0;
    float v1 = v[(size_t)s * DF + 64 + lane] + ee1;
    agg0 += w * v0;
    agg1 += w * v1;
  }

  float o0 = out[(size_t)node * DF + lane];
  float o1 = out[(size_t)node * DF + 64 + lane];
  if (ssum > 0.f) {
    o0 += agg0 / ssum;
    o1 += agg1 / ssum;
  }
  if (relu) {
    o0 = fmaxf(o0, 0.f);
    o1 = fmaxf(o1, 0.f);
  }
  out[(size_t)node * DF + lane] = o0;
  out[(size_t)node * DF + 64 + lane] = o1;
}

// ---------------- launch ----------------

extern "C" void kernel_launch(void* const* d_in, const int* in_sizes, int n_in,
                              void* d_out, int out_size, void* d_ws, size_t ws_size,
                              hipStream_t stream) {
  const float* x_user = (const float*)d_in[0];
  const float* x_item = (const float*)d_in[1];
  const float* ea_ui = (const float*)d_in[2];
  const float* ea_iu = (const float*)d_in[3];
  const float* Wq = (const float*)d_in[4];
  const float* bq = (const float*)d_in[5];
  const float* Wk = (const float*)d_in[6];
  const float* bk = (const float*)d_in[7];
  const float* Wv = (const float*)d_in[8];
  const float* bv = (const float*)d_in[9];
  const float* We = (const float*)d_in[10];
  const float* be = (const float*)d_in[11];
  const float* Ws = (const float*)d_in[12];
  const float* bs = (const float*)d_in[13];
  const int* ei_ui = (const int*)d_in[14];
  const int* ei_iu = (const int*)d_in[15];
  float* out = (float*)d_out;

  // workspace partition
  char* wp = (char*)d_ws;
  auto alloc = [&](size_t bytes) {
    void* p = (void*)wp;
    wp += (bytes + 255) & ~(size_t)255;
    return p;
  };
  const size_t NB = (size_t)NNODE * DF;  // 12.8M floats
  float* qbuf = (float*)alloc(NB * 4);
  float* kbuf = (float*)alloc(NB * 4);
  float* vbuf = (float*)alloc(NB * 4);
  float* xu1 = (float*)alloc(NB * 4);
  float* xi1 = (float*)alloc(NB * 4);
  int* cnt = (int*)alloc((NNODE + 1) * 4);
  int* off_ui = (int*)alloc((NNODE + 1) * 4);
  int* off_iu = (int*)alloc((NNODE + 1) * 4);
  int* eid_ui = (int*)alloc((size_t)NEDGE * 4);
  int* eid_iu = (int*)alloc((size_t)NEDGE * 4);

  const int EB = (NEDGE + 255) / 256;         // 3125
  const int PB = (NNODE + 63) / 64;           // 1563
  const int AB = (NNODE + 3) / 4;             // 25001

  // CSR by destination (topology constant across layers -> build once per call)
  auto build_csr = [&](const int* dstarr, int* offp, int* eidp) {
    hipMemsetAsync(cnt, 0, (NNODE + 1) * sizeof(int), stream);
    hist_kernel<<<EB, 256, 0, stream>>>(dstarr, cnt, NEDGE);
    scan_kernel<<<1, 1024, 0, stream>>>(cnt, offp, NNODE);
    hipMemcpyAsync(cnt, offp, NNODE * sizeof(int), hipMemcpyDeviceToDevice, stream);
    scatter_kernel<<<EB, 256, 0, stream>>>(dstarr, cnt, eidp, NEDGE);
  };
  build_csr(ei_ui + NEDGE, off_ui, eid_ui);  // ui edges: dst = items
  build_csr(ei_iu + NEDGE, off_iu, eid_iu);  // iu edges: dst = users

  // one TransformerConv: wsel = l*2 + d selects the weight slice
  auto run_conv = [&](const float* xs, const float* xd, int wsel, const float* eattr,
                      const int* esrc, const int* offp, const int* eidp, float* outp, int relu) {
    proj2_kernel<<<PB, 256, 0, stream>>>(xd, NNODE,
        Wq + (size_t)wsel * DF * DF, bq + (size_t)wsel * DF, qbuf,
        Ws + (size_t)wsel * DF * DF, bs + (size_t)wsel * DF, outp);
    proj2_kernel<<<PB, 256, 0, stream>>>(xs, NNODE,
        Wk + (size_t)wsel * DF * DF, bk + (size_t)wsel * DF, kbuf,
        Wv + (size_t)wsel * DF * DF, bv + (size_t)wsel * DF, vbuf);
    edge_attn_kernel<<<AB, 256, 0, stream>>>(qbuf, kbuf, vbuf, eattr,
        We + (size_t)wsel * EDIM * DF, be + (size_t)wsel * DF,
        esrc, offp, eidp, outp, NNODE, relu);
  };

  // layer 0 (ReLU)
  run_conv(x_user, x_item, 0, ea_ui, ei_ui, off_ui, eid_ui, xi1, 1);  // -> xi_new
  run_conv(x_item, x_user, 1, ea_iu, ei_iu, off_iu, eid_iu, xu1, 1);  // -> xu_new
  // layer 1 (no ReLU), outputs straight into d_out = [x_user | x_item]
  run_conv(xu1, xi1, 2, ea_ui, ei_ui, off_ui, eid_ui, out + NB, 0);
  run_conv(xi1, xu1, 3, ea_iu, ei_iu, off_iu, eid_iu, out, 0);
}

// Round 2
// 3866.406 us; speedup vs baseline: 1.0406x; 1.0406x over previous
//
#include <hip/hip_runtime.h>
#include <hip/hip_bf16.h>
#include <math.h>

#define NNODE 100000
#define NEDGE 800000
#define DF 128
#define EDIM 32

typedef __attribute__((ext_vector_type(8))) short short8v;
typedef __attribute__((ext_vector_type(4))) float f32x4;

__device__ inline short bf16_of(float x) {
  __hip_bfloat16 h = __float2bfloat16(x);
  return *reinterpret_cast<short*>(&h);
}

// ---------------- CSR build ----------------

__global__ void hist_kernel(const int* __restrict__ dst, int* __restrict__ cnt, int ne) {
  int i = blockIdx.x * blockDim.x + threadIdx.x;
  if (i < ne) atomicAdd(&cnt[dst[i]], 1);
}

__global__ __launch_bounds__(1024) void scan_kernel(const int* __restrict__ cnt,
                                                    int* __restrict__ off, int n) {
  __shared__ int lds[1024];
  __shared__ int carry_s;
  int t = threadIdx.x;
  if (t == 0) carry_s = 0;
  __syncthreads();
  for (int base = 0; base < n; base += 8192) {
    int x[8];
    int s = 0;
#pragma unroll
    for (int i = 0; i < 8; ++i) {
      int idx = base + t * 8 + i;
      x[i] = (idx < n) ? cnt[idx] : 0;
      s += x[i];
    }
    lds[t] = s;
    __syncthreads();
#pragma unroll
    for (int st = 1; st < 1024; st <<= 1) {
      int v2 = (t >= st) ? lds[t - st] : 0;
      __syncthreads();
      lds[t] += v2;
      __syncthreads();
    }
    int excl = carry_s + lds[t] - s;
#pragma unroll
    for (int i = 0; i < 8; ++i) {
      int idx = base + t * 8 + i;
      if (idx < n) off[idx] = excl;
      excl += x[i];
    }
    __syncthreads();
    if (t == 0) carry_s += lds[1023];
    __syncthreads();
  }
  if (t == 0) off[n] = carry_s;
}

__global__ void scatter_kernel(const int* __restrict__ dst, int* __restrict__ cursor,
                               int* __restrict__ eid, int ne) {
  int i = blockIdx.x * blockDim.x + threadIdx.x;
  if (i < ne) {
    int p = atomicAdd(&cursor[dst[i]], 1);
    eid[p] = i;
  }
}

// ---------------- pre-casts ----------------

__global__ void cast_bf16_kernel(const float* __restrict__ x, short* __restrict__ y, int n4) {
  int i = blockIdx.x * blockDim.x + threadIdx.x;
  if (i < n4) {
    float4 v = ((const float4*)x)[i];
    short4 o;
    o.x = bf16_of(v.x); o.y = bf16_of(v.y); o.z = bf16_of(v.z); o.w = bf16_of(v.w);
    ((short4*)y)[i] = o;
  }
}

// W [nmat][128(c)][128(h)] f32 -> Wt [nmat][128(h)][128(c)] bf16
__global__ void transW_kernel(const float* __restrict__ W, short* __restrict__ Wt, int total) {
  for (int i = blockIdx.x * blockDim.x + threadIdx.x; i < total; i += gridDim.x * blockDim.x) {
    int m = i >> 14, rem = i & 16383;
    int c = rem >> 7, h = rem & 127;
    Wt[(size_t)m * 16384 + h * DF + c] = bf16_of(W[i]);
  }
}

// ---------------- MFMA projections: Y1 = X@W1+b1, Y2 = X@W2+b2 ----------------
// Xb bf16 [n,128]; Wt* bf16 pre-transposed [h][c]; Y f32.
__global__ __launch_bounds__(256) void proj_mfma_kernel(
    const short* __restrict__ Xb, int nrows,
    const short* __restrict__ Wt1, const float* __restrict__ b1, float* __restrict__ Y1,
    const short* __restrict__ Wt2, const float* __restrict__ b2, float* __restrict__ Y2) {
  __shared__ short Xs[128 * 128];
  __shared__ short Ws[128 * 128];
  int t = threadIdx.x;
  int row0 = blockIdx.x * 128;

  // stage X tile (bf16 copy, XOR-swizzled 16B chunks)
#pragma unroll
  for (int i = 0; i < 16; ++i) {
    int idx4 = t + i * 256;     // short4 index; 32 per row
    int row = idx4 >> 5;
    int q4 = idx4 & 31;
    short4 val; val.x = val.y = val.z = val.w = 0;
    if (row0 + row < nrows) val = ((const short4*)(Xb + (size_t)(row0 + row) * DF))[q4];
    int chunk = q4 >> 1, within = (q4 & 1) * 4;
    *(short4*)&Xs[row * 128 + ((chunk ^ (row & 15)) << 3) + within] = val;
  }

  int lane = t & 63, wave = t >> 6;
  int wm = wave >> 1, wn = wave & 1;
  int fr = lane & 15;
  int kb = lane >> 4;

  for (int p = 0; p < 2; ++p) {
    const short* Wg = p ? Wt2 : Wt1;
    if (p) __syncthreads();  // protect Ws overwrite
#pragma unroll
    for (int i = 0; i < 16; ++i) {
      int idx4 = t + i * 256;
      int row = idx4 >> 5;     // = output col h
      int q4 = idx4 & 31;
      short4 val = ((const short4*)(Wg + (size_t)row * DF))[q4];
      int chunk = q4 >> 1, within = (q4 & 1) * 4;
      *(short4*)&Ws[row * 128 + ((chunk ^ (row & 15)) << 3) + within] = val;
    }
    __syncthreads();

    f32x4 acc[4][4];
#pragma unroll
    for (int m = 0; m < 4; ++m)
#pragma unroll
      for (int nf = 0; nf < 4; ++nf) acc[m][nf] = (f32x4){0.f, 0.f, 0.f, 0.f};

#pragma unroll
    for (int kk = 0; kk < 4; ++kk) {
      int chunk = kk * 4 + kb;
      short8v a[4], b[4];
#pragma unroll
      for (int m = 0; m < 4; ++m) {
        int row = wm * 64 + m * 16 + fr;
        a[m] = *(const short8v*)&Xs[row * 128 + ((chunk ^ (row & 15)) << 3)];
      }
#pragma unroll
      for (int nf = 0; nf < 4; ++nf) {
        int col = wn * 64 + nf * 16 + fr;
        b[nf] = *(const short8v*)&Ws[col * 128 + ((chunk ^ (col & 15)) << 3)];
      }
#pragma unroll
      for (int m = 0; m < 4; ++m)
#pragma unroll
        for (int nf = 0; nf < 4; ++nf)
          acc[m][nf] = __builtin_amdgcn_mfma_f32_16x16x32_bf16(a[m], b[nf], acc[m][nf], 0, 0, 0);
    }

    const float* bb = p ? b2 : b1;
    float* Y = p ? Y2 : Y1;
#pragma unroll
    for (int nf = 0; nf < 4; ++nf) {
      int col = wn * 64 + nf * 16 + fr;
      float bv = bb[col];
#pragma unroll
      for (int m = 0; m < 4; ++m) {
        int rbase = row0 + wm * 64 + m * 16 + (lane >> 4) * 4;
#pragma unroll
        for (int r = 0; r < 4; ++r) {
          int row = rbase + r;
          if (row < nrows) Y[(size_t)row * DF + col] = acc[m][nf][r] + bv;
        }
      }
    }
  }
}

// ---------------- gq = We @ q per node (pre-scaled by 0.5 for dup-lane reduce) ----------------
__global__ __launch_bounds__(256) void gq_kernel(const float* __restrict__ q,
                                                 const float* __restrict__ We,
                                                 float* __restrict__ gq, int n) {
  int gid = blockIdx.x * 256 + threadIdx.x;
  int node = gid >> 5, c = gid & 31;
  if (node >= n) return;
  const float4* q4 = (const float4*)(q + (size_t)node * DF);
  const float4* w4 = (const float4*)(We + (size_t)c * DF);
  float acc = 0.f;
#pragma unroll 8
  for (int i = 0; i < 32; ++i) {
    float4 a = q4[i], b = w4[i];
    acc += a.x * b.x + a.y * b.y + a.z * b.z + a.w * b.w;
  }
  gq[gid] = acc * 0.5f;
}

// ---------------- fused edge attention (grid-stride wave per node, 4-edge batches) ----------------
__global__ __launch_bounds__(256) void edge_attn_kernel(
    const float* __restrict__ q, const float* __restrict__ k, const float* __restrict__ v,
    const float* __restrict__ gq,  // [n,32]
    const float* __restrict__ ea,  // [E,32]
    const float* __restrict__ We,  // [32,128]
    const float* __restrict__ be,  // [128]
    const int* __restrict__ esrc, const int* __restrict__ off, const int* __restrict__ eid,
    float* __restrict__ out, short* __restrict__ outb, int nd, int relu, int nwaves) {
  int lane = threadIdx.x & 63;
  int gw = blockIdx.x * (blockDim.x >> 6) + (threadIdx.x >> 6);
  int c = lane & 31;
  const float scale = 0.08838834764831845f;  // 128^-0.5

  for (int node = gw; node < nd; node += nwaves) {
    int e0 = off[node], e1 = off[node + 1];
    float2 q01 = *(const float2*)(q + (size_t)node * DF + 2 * lane);
    float gqc = gq[node * 32 + c];
    float2 be2 = *(const float2*)(be + 2 * lane);
    // qbe = q . be (once per node)
    float pb = q01.x * be2.x + q01.y * be2.y;
#pragma unroll
    for (int o = 32; o; o >>= 1) pb += __shfl_xor(pb, o);

    float m = -INFINITY, ssum = 0.f, agg0 = 0.f, agg1 = 0.f, acce = 0.f;

    for (int j0 = e0; j0 < e1; j0 += 4) {
      int nb = e1 - j0;
      if (nb > 4) nb = 4;
      int ei[4], si[4];
      float av[4];
      float2 kv[4], vv[4];
#pragma unroll
      for (int i = 0; i < 4; ++i) ei[i] = (i < nb) ? eid[j0 + i] : 0;
#pragma unroll
      for (int i = 0; i < 4; ++i) si[i] = esrc[ei[i]];
#pragma unroll
      for (int i = 0; i < 4; ++i) av[i] = (i < nb) ? ea[(size_t)ei[i] * EDIM + c] : 0.f;
#pragma unroll
      for (int i = 0; i < 4; ++i) kv[i] = *(const float2*)(k + (size_t)si[i] * DF + 2 * lane);
#pragma unroll
      for (int i = 0; i < 4; ++i) vv[i] = *(const float2*)(v + (size_t)si[i] * DF + 2 * lane);

      float a[4];
#pragma unroll
      for (int i = 0; i < 4; ++i) {
        float p = q01.x * kv[i].x + q01.y * kv[i].y + av[i] * gqc;
#pragma unroll
        for (int o = 32; o; o >>= 1) p += __shfl_xor(p, o);
        a[i] = (i < nb) ? (p + pb) * scale : -INFINITY;
      }
      float mn = m;
#pragma unroll
      for (int i = 0; i < 4; ++i) mn = fmaxf(mn, a[i]);
      if (mn > m) {
        float f = __expf(m - mn);
        ssum *= f; agg0 *= f; agg1 *= f; acce *= f;
        m = mn;
      }
#pragma unroll
      for (int i = 0; i < 4; ++i) {
        float w = __expf(a[i] - m);
        ssum += w;
        agg0 += w * vv[i].x;
        agg1 += w * vv[i].y;
        acce += w * av[i];
      }
    }

    float2 o2 = *(const float2*)(out + (size_t)node * DF + 2 * lane);
    if (ssum > 0.f) {
      float inv = 1.0f / ssum;
      float t0 = 0.f, t1 = 0.f;
#pragma unroll
      for (int cc = 0; cc < 32; ++cc) {
        float ac = __shfl(acce, cc, 64);
        float2 w2 = *(const float2*)(We + cc * DF + 2 * lane);
        t0 += ac * w2.x;
        t1 += ac * w2.y;
      }
      o2.x += (agg0 + t0) * inv + be2.x;
      o2.y += (agg1 + t1) * inv + be2.y;
    }
    if (relu) {
      o2.x = fmaxf(o2.x, 0.f);
      o2.y = fmaxf(o2.y, 0.f);
    }
    *(float2*)(out + (size_t)node * DF + 2 * lane) = o2;
    if (outb) {
      short2 ob;
      ob.x = bf16_of(o2.x);
      ob.y = bf16_of(o2.y);
      *(short2*)(outb + (size_t)node * DF + 2 * lane) = ob;
    }
  }
}

// ---------------- launch ----------------

extern "C" void kernel_launch(void* const* d_in, const int* in_sizes, int n_in,
                              void* d_out, int out_size, void* d_ws, size_t ws_size,
                              hipStream_t stream) {
  const float* x_user = (const float*)d_in[0];
  const float* x_item = (const float*)d_in[1];
  const float* ea_ui = (const float*)d_in[2];
  const float* ea_iu = (const float*)d_in[3];
  const float* Wq = (const float*)d_in[4];
  const float* bq = (const float*)d_in[5];
  const float* Wk = (const float*)d_in[6];
  const float* bk = (const float*)d_in[7];
  const float* Wv = (const float*)d_in[8];
  const float* bv = (const float*)d_in[9];
  const float* We = (const float*)d_in[10];
  const float* be = (const float*)d_in[11];
  const float* Ws = (const float*)d_in[12];
  const float* bs = (const float*)d_in[13];
  const int* ei_ui = (const int*)d_in[14];
  const int* ei_iu = (const int*)d_in[15];
  float* out = (float*)d_out;

  char* wp = (char*)d_ws;
  auto alloc = [&](size_t bytes) {
    void* p = (void*)wp;
    wp += (bytes + 255) & ~(size_t)255;
    return p;
  };
  const size_t NB = (size_t)NNODE * DF;
  short* xub = (short*)alloc(NB * 2);
  short* xib = (short*)alloc(NB * 2);
  short* xu1b = (short*)alloc(NB * 2);
  short* xi1b = (short*)alloc(NB * 2);
  float* qbuf = (float*)alloc(NB * 4);
  float* kbuf = (float*)alloc(NB * 4);
  float* vbuf = (float*)alloc(NB * 4);
  float* tmpout = (float*)alloc(NB * 4);
  float* gqbuf = (float*)alloc((size_t)NNODE * 32 * 4);
  short* wtq = (short*)alloc(4 * 16384 * 2);
  short* wtk = (short*)alloc(4 * 16384 * 2);
  short* wtv = (short*)alloc(4 * 16384 * 2);
  short* wts = (short*)alloc(4 * 16384 * 2);
  int* cnt = (int*)alloc((NNODE + 1) * 4);
  int* off_ui = (int*)alloc((NNODE + 1) * 4);
  int* off_iu = (int*)alloc((NNODE + 1) * 4);
  int* eid_ui = (int*)alloc((size_t)NEDGE * 4);
  int* eid_iu = (int*)alloc((size_t)NEDGE * 4);

  const int EB = (NEDGE + 255) / 256;
  const int PB = (NNODE + 127) / 128;  // 782
  const int CB = (int)(NB / 4 + 255) / 256;

  // pre-casts
  cast_bf16_kernel<<<CB, 256, 0, stream>>>(x_user, xub, (int)(NB / 4));
  cast_bf16_kernel<<<CB, 256, 0, stream>>>(x_item, xib, (int)(NB / 4));
  transW_kernel<<<256, 256, 0, stream>>>(Wq, wtq, 4 * 16384);
  transW_kernel<<<256, 256, 0, stream>>>(Wk, wtk, 4 * 16384);
  transW_kernel<<<256, 256, 0, stream>>>(Wv, wtv, 4 * 16384);
  transW_kernel<<<256, 256, 0, stream>>>(Ws, wts, 4 * 16384);

  // CSR by destination
  auto build_csr = [&](const int* dstarr, int* offp, int* eidp) {
    hipMemsetAsync(cnt, 0, (NNODE + 1) * sizeof(int), stream);
    hist_kernel<<<EB, 256, 0, stream>>>(dstarr, cnt, NEDGE);
    scan_kernel<<<1, 1024, 0, stream>>>(cnt, offp, NNODE);
    hipMemcpyAsync(cnt, offp, NNODE * sizeof(int), hipMemcpyDeviceToDevice, stream);
    scatter_kernel<<<EB, 256, 0, stream>>>(dstarr, cnt, eidp, NEDGE);
  };
  build_csr(ei_ui + NEDGE, off_ui, eid_ui);
  build_csr(ei_iu + NEDGE, off_iu, eid_iu);

  auto run_conv = [&](const short* xsb, const short* xdb, int wsel, const float* eattr,
                      const int* esrcp, const int* offp, const int* eidp,
                      float* outp, short* outbp, int relu) {
    proj_mfma_kernel<<<PB, 256, 0, stream>>>(xdb, NNODE,
        wtq + (size_t)wsel * DF * DF, bq + (size_t)wsel * DF, qbuf,
        wts + (size_t)wsel * DF * DF, bs + (size_t)wsel * DF, outp);
    proj_mfma_kernel<<<PB, 256, 0, stream>>>(xsb, NNODE,
        wtk + (size_t)wsel * DF * DF, bk + (size_t)wsel * DF, kbuf,
        wtv + (size_t)wsel * DF * DF, bv + (size_t)wsel * DF, vbuf);
    gq_kernel<<<(NNODE * 32) / 256 + 1, 256, 0, stream>>>(
        qbuf, We + (size_t)wsel * EDIM * DF, gqbuf, NNODE);
    edge_attn_kernel<<<4096, 256, 0, stream>>>(qbuf, kbuf, vbuf, gqbuf, eattr,
        We + (size_t)wsel * EDIM * DF, be + (size_t)wsel * DF,
        esrcp, offp, eidp, outp, outbp, NNODE, relu, 4096 * 4);
  };

  // layer 0 (ReLU), f32 out into shared tmp, bf16 mirror kept for layer 1
  run_conv(xub, xib, 0, ea_ui, ei_ui, off_ui, eid_ui, tmpout, xi1b, 1);
  run_conv(xib, xub, 1, ea_iu, ei_iu, off_iu, eid_iu, tmpout, xu1b, 1);
  // layer 1 (no ReLU) straight into d_out = [x_user | x_item]
  run_conv(xu1b, xi1b, 2, ea_ui, ei_ui, off_ui, eid_ui, out + NB, nullptr, 0);
  run_conv(xi1b, xu1b, 3, ea_iu, ei_iu, off_iu, eid_iu, out, nullptr, 0);
}

// Round 3
// 2140.617 us; speedup vs baseline: 1.8796x; 1.8062x over previous
//
#include <hip/hip_runtime.h>
#include <hip/hip_bf16.h>
#include <math.h>

#define NNODE 100000
#define NEDGE 800000
#define DF 128
#define EDIM 32

typedef __attribute__((ext_vector_type(8))) short short8v;
typedef __attribute__((ext_vector_type(4))) float f32x4;
typedef unsigned short u16;

__device__ inline short bf16_of(float x) {
  __hip_bfloat16 h = __float2bfloat16(x);
  return *reinterpret_cast<short*>(&h);
}
__device__ inline float f_of_bf16(u16 u) {
  union { unsigned int i; float f; } c;
  c.i = ((unsigned int)u) << 16;
  return c.f;
}

// ---------------- fused pre-casts ----------------

__global__ void cast2_kernel(const float* __restrict__ a, const float* __restrict__ b,
                             short* __restrict__ ya, short* __restrict__ yb, int n4) {
  int i = blockIdx.x * blockDim.x + threadIdx.x;
  if (i < 2 * n4) {
    const float* s = (i < n4) ? a : b;
    short* y = (i < n4) ? ya : yb;
    int j = (i < n4) ? i : i - n4;
    float4 v = ((const float4*)s)[j];
    short4 o;
    o.x = bf16_of(v.x); o.y = bf16_of(v.y); o.z = bf16_of(v.z); o.w = bf16_of(v.w);
    ((short4*)y)[j] = o;
  }
}

// all 4 weight families -> transposed bf16 [kind][mat][h][c]
__global__ void transW_kernel(const float* __restrict__ Wq, const float* __restrict__ Wk,
                              const float* __restrict__ Wv, const float* __restrict__ Ws,
                              short* __restrict__ wt) {
  int i = blockIdx.x * blockDim.x + threadIdx.x;
  if (i >= 4 * 4 * 16384) return;
  int kind = i >> 16;
  int rem = i & 65535;
  int m = rem >> 14, rr = rem & 16383;
  int c = rr >> 7, h = rr & 127;
  const float* W = kind == 0 ? Wq : kind == 1 ? Wk : kind == 2 ? Wv : Ws;
  wt[(size_t)kind * 65536 + m * 16384 + h * DF + c] = bf16_of(W[(size_t)m * 16384 + c * DF + h]);
}

// ---------------- CSR build (both edge types fused) ----------------

__global__ void hist2_kernel(const int* __restrict__ d0, const int* __restrict__ d1,
                             int* __restrict__ cnt, int ne) {
  int i = blockIdx.x * blockDim.x + threadIdx.x;
  if (i < 2 * ne) {
    int t = (i >= ne);
    int e = i - t * ne;
    const int* d = t ? d1 : d0;
    atomicAdd(&cnt[t * (NNODE + 1) + d[e]], 1);
  }
}

__global__ __launch_bounds__(1024) void scan_kernel(const int* __restrict__ cntg,
                                                    int* __restrict__ offg, int n) {
  const int* cnt = cntg + blockIdx.x * (NNODE + 1);
  int* off = offg + blockIdx.x * (NNODE + 1);
  __shared__ int lds[1024];
  __shared__ int carry_s;
  int t = threadIdx.x;
  if (t == 0) carry_s = 0;
  __syncthreads();
  for (int base = 0; base < n; base += 8192) {
    int x[8];
    int s = 0;
#pragma unroll
    for (int i = 0; i < 8; ++i) {
      int idx = base + t * 8 + i;
      x[i] = (idx < n) ? cnt[idx] : 0;
      s += x[i];
    }
    lds[t] = s;
    __syncthreads();
#pragma unroll
    for (int st = 1; st < 1024; st <<= 1) {
      int v2 = (t >= st) ? lds[t - st] : 0;
      __syncthreads();
      lds[t] += v2;
      __syncthreads();
    }
    int excl = carry_s + lds[t] - s;
#pragma unroll
    for (int i = 0; i < 8; ++i) {
      int idx = base + t * 8 + i;
      if (idx < n) off[idx] = excl;
      excl += x[i];
    }
    __syncthreads();
    if (t == 0) carry_s += lds[1023];
    __syncthreads();
  }
  if (t == 0) off[n] = carry_s;
}

// scatter: permute src + edge-attr (bf16) into CSR order; eid kept for fallback
__global__ void scatter2_kernel(const int* __restrict__ s0, const int* __restrict__ d0,
                                const float* __restrict__ ea0,
                                const int* __restrict__ s1, const int* __restrict__ d1,
                                const float* __restrict__ ea1,
                                int* __restrict__ cur, int* __restrict__ src0c,
                                int* __restrict__ src1c, int* __restrict__ eid0c,
                                int* __restrict__ eid1c, u16* __restrict__ eac0,
                                u16* __restrict__ eac1, int ne) {
  int i = blockIdx.x * blockDim.x + threadIdx.x;
  if (i >= 2 * ne) return;
  int t = (i >= ne);
  int e = i - t * ne;
  const int* dd = t ? d1 : d0;
  const int* ss = t ? s1 : s0;
  const float* ea = t ? ea1 : ea0;
  int* sc = t ? src1c : src0c;
  int* ec = t ? eid1c : eid0c;
  u16* ac = t ? eac1 : eac0;
  int p = atomicAdd(&cur[t * (NNODE + 1) + dd[e]], 1);
  sc[p] = ss[e];
  ec[p] = e;
  if (ac) {
    const float4* r4 = (const float4*)(ea + (size_t)e * EDIM);
    u16* w = ac + (size_t)p * EDIM;
#pragma unroll
    for (int j = 0; j < 8; ++j) {
      float4 v = r4[j];
      short4 o;
      o.x = bf16_of(v.x); o.y = bf16_of(v.y); o.z = bf16_of(v.z); o.w = bf16_of(v.w);
      *(short4*)(w + j * 4) = o;
    }
  }
}

// ---------------- fused MFMA projections: q,skip,k,v in one dispatch ----------------
// operand-swapped mfma: D[h][node] -> lane stores float4/short4 along h
__global__ __launch_bounds__(256) void proj_kernel(
    const short* __restrict__ xd, const short* __restrict__ xs, int n,
    const short* __restrict__ wtq, const float* __restrict__ bq, short* __restrict__ qb,
    const short* __restrict__ wts, const float* __restrict__ bs, float* __restrict__ skipf,
    const short* __restrict__ wtk, const float* __restrict__ bk, short* __restrict__ kb,
    const short* __restrict__ wtv, const float* __restrict__ bv, short* __restrict__ vb) {
  __shared__ short Xs[128 * 128];
  int t = threadIdx.x;
  int row0 = blockIdx.x * 128;
  int job = blockIdx.y;
  const short* X = job ? xs : xd;

  // stage X tile, XOR-swizzled 16B chunks
#pragma unroll
  for (int i = 0; i < 16; ++i) {
    int idx4 = t + i * 256;
    int row = idx4 >> 5;
    int q4 = idx4 & 31;
    short4 val; val.x = val.y = val.z = val.w = 0;
    if (row0 + row < n) val = ((const short4*)(X + (size_t)(row0 + row) * DF))[q4];
    int chunk = q4 >> 1, within = (q4 & 1) * 4;
    *(short4*)&Xs[row * 128 + ((chunk ^ (row & 15)) << 3) + within] = val;
  }
  __syncthreads();

  int lane = t & 63, wave = t >> 6;
  int wm = wave >> 1, wh = wave & 1;
  int fr = lane & 15, kq = lane >> 4;

  for (int p = 0; p < 2; ++p) {
    const short* Wt = job ? (p ? wtv : wtk) : (p ? wts : wtq);
    const float* bb = job ? (p ? bv : bk) : (p ? bs : bq);
    f32x4 acc[4][4];
#pragma unroll
    for (int m = 0; m < 4; ++m)
#pragma unroll
      for (int nf = 0; nf < 4; ++nf) acc[m][nf] = (f32x4){0.f, 0.f, 0.f, 0.f};

#pragma unroll
    for (int kk = 0; kk < 4; ++kk) {
      short8v xf[4], wf[4];
      int chunk = kk * 4 + kq;
#pragma unroll
      for (int m = 0; m < 4; ++m) {
        int row = wm * 64 + m * 16 + fr;
        xf[m] = *(const short8v*)&Xs[row * 128 + ((chunk ^ (row & 15)) << 3)];
      }
#pragma unroll
      for (int nf = 0; nf < 4; ++nf) {
        int h = wh * 64 + nf * 16 + fr;
        wf[nf] = *(const short8v*)(Wt + (size_t)h * DF + kk * 32 + kq * 8);
      }
#pragma unroll
      for (int m = 0; m < 4; ++m)
#pragma unroll
        for (int nf = 0; nf < 4; ++nf)
          acc[m][nf] = __builtin_amdgcn_mfma_f32_16x16x32_bf16(wf[nf], xf[m], acc[m][nf], 0, 0, 0);
    }

    short* Yb = job ? (p ? vb : kb) : (p ? nullptr : qb);
    float* Yf = (!job && p) ? skipf : nullptr;
#pragma unroll
    for (int nf = 0; nf < 4; ++nf) {
      float4 b4 = *(const float4*)(bb + wh * 64 + nf * 16 + kq * 4);
#pragma unroll
      for (int m = 0; m < 4; ++m) {
        int node = row0 + wm * 64 + m * 16 + fr;
        if (node < n) {
          f32x4 r = acc[m][nf];
          float v0 = r[0] + b4.x, v1 = r[1] + b4.y, v2 = r[2] + b4.z, v3 = r[3] + b4.w;
          size_t o = (size_t)node * DF + wh * 64 + nf * 16 + kq * 4;
          if (Yf) {
            *(float4*)(Yf + o) = make_float4(v0, v1, v2, v3);
          } else {
            short4 s4;
            s4.x = bf16_of(v0); s4.y = bf16_of(v1); s4.z = bf16_of(v2); s4.w = bf16_of(v3);
            *(short4*)(Yb + o) = s4;
          }
        }
      }
    }
  }
}

// ---------------- gq = 0.5 * We @ q per node ----------------
__global__ __launch_bounds__(256) void gq_kernel(const short* __restrict__ q,
                                                 const float* __restrict__ We,
                                                 float* __restrict__ gq, int n) {
  int gid = blockIdx.x * 256 + threadIdx.x;
  int node = gid >> 5, c = gid & 31;
  if (node >= n) return;
  const ushort4* q4 = (const ushort4*)(q + (size_t)node * DF);
  const float4* w4 = (const float4*)(We + (size_t)c * DF);
  float acc = 0.f;
#pragma unroll 8
  for (int i = 0; i < 32; ++i) {
    ushort4 u = q4[i];
    float4 b = w4[i];
    acc += f_of_bf16(u.x) * b.x + f_of_bf16(u.y) * b.y + f_of_bf16(u.z) * b.z +
           f_of_bf16(u.w) * b.w;
  }
  gq[gid] = acc * 0.5f;
}

// ---------------- fused edge attention: 1 wave / node, 8-edge batches ----------------
template <int PERM>
__global__ __launch_bounds__(256) void edge_attn_kernel(
    const short* __restrict__ qb, const short* __restrict__ kb, const short* __restrict__ vb,
    const float* __restrict__ gq, const float* __restrict__ We, const float* __restrict__ be,
    const int* __restrict__ src_csr, const int* __restrict__ off,
    const u16* __restrict__ eac, const float* __restrict__ ea, const int* __restrict__ eidc,
    const float* __restrict__ skipf, float* __restrict__ outf, short* __restrict__ outb,
    int nd, int relu) {
  int lane = threadIdx.x & 63;
  int node = blockIdx.x * 4 + (threadIdx.x >> 6);
  if (node >= nd) return;
  int c = lane & 31;
  int e0 = off[node], e1 = off[node + 1];
  size_t ob = (size_t)node * DF + 2 * lane;

  ushort2 qu = *(const ushort2*)((const u16*)qb + ob);
  float2 q01 = make_float2(f_of_bf16(qu.x), f_of_bf16(qu.y));
  float gqc = gq[node * 32 + c];
  float2 be2 = *(const float2*)(be + 2 * lane);
  float pb = q01.x * be2.x + q01.y * be2.y;
#pragma unroll
  for (int o = 32; o; o >>= 1) pb += __shfl_xor(pb, o);

  const float scale = 0.08838834764831845f;  // 128^-0.5
  float m = -INFINITY, ssum = 0.f, ag0 = 0.f, ag1 = 0.f, acce = 0.f;

  for (int j0 = e0; j0 < e1; j0 += 8) {
    int si[8];
    float av[8], a[8];
    float2 kv[8], vv[8];
#pragma unroll
    for (int i = 0; i < 8; ++i) {
      int jj = (j0 + i < e1) ? j0 + i : e1 - 1;
      si[i] = src_csr[jj];
    }
#pragma unroll
    for (int i = 0; i < 8; ++i) {
      int jj = (j0 + i < e1) ? j0 + i : e1 - 1;
      av[i] = PERM ? f_of_bf16(eac[(size_t)jj * EDIM + c])
                   : ea[(size_t)eidc[jj] * EDIM + c];
    }
#pragma unroll
    for (int i = 0; i < 8; ++i) {
      ushort2 u = *(const ushort2*)((const u16*)kb + (size_t)si[i] * DF + 2 * lane);
      kv[i] = make_float2(f_of_bf16(u.x), f_of_bf16(u.y));
    }
#pragma unroll
    for (int i = 0; i < 8; ++i) {
      ushort2 u = *(const ushort2*)((const u16*)vb + (size_t)si[i] * DF + 2 * lane);
      vv[i] = make_float2(f_of_bf16(u.x), f_of_bf16(u.y));
    }
#pragma unroll
    for (int i = 0; i < 8; ++i) {
      float p = q01.x * kv[i].x + q01.y * kv[i].y + av[i] * gqc;
#pragma unroll
      for (int o = 32; o; o >>= 1) p += __shfl_xor(p, o);
      a[i] = (j0 + i < e1) ? (p + pb) * scale : -INFINITY;
    }
    float mn = m;
#pragma unroll
    for (int i = 0; i < 8; ++i) mn = fmaxf(mn, a[i]);
    if (mn > m) {  // wave-uniform
      float f = __expf(m - mn);
      ssum *= f; ag0 *= f; ag1 *= f; acce *= f;
      m = mn;
    }
#pragma unroll
    for (int i = 0; i < 8; ++i) {
      float w = __expf(a[i] - m);
      ssum += w;
      ag0 += w * vv[i].x;
      ag1 += w * vv[i].y;
      acce += w * av[i];
    }
  }

  float2 sk = *(const float2*)(skipf + ob);
  float o0 = sk.x, o1 = sk.y;
  if (ssum > 0.f) {
    float inv = 1.f / ssum;
    float t0 = 0.f, t1 = 0.f;
#pragma unroll
    for (int cc = 0; cc < 32; ++cc) {
      float ac = __shfl(acce, cc, 64);
      float2 w2 = *(const float2*)(We + cc * DF + 2 * lane);
      t0 += ac * w2.x;
      t1 += ac * w2.y;
    }
    o0 += (ag0 + t0) * inv + be2.x;
    o1 += (ag1 + t1) * inv + be2.y;
  }
  if (relu) {
    o0 = fmaxf(o0, 0.f);
    o1 = fmaxf(o1, 0.f);
  }
  if (outf) *(float2*)(outf + ob) = make_float2(o0, o1);
  if (outb) {
    short2 s;
    s.x = bf16_of(o0);
    s.y = bf16_of(o1);
    *(short2*)(outb + ob) = s;
  }
}

// ---------------- launch ----------------

extern "C" void kernel_launch(void* const* d_in, const int* in_sizes, int n_in,
                              void* d_out, int out_size, void* d_ws, size_t ws_size,
                              hipStream_t stream) {
  const float* x_user = (const float*)d_in[0];
  const float* x_item = (const float*)d_in[1];
  const float* ea_ui = (const float*)d_in[2];
  const float* ea_iu = (const float*)d_in[3];
  const float* Wq = (const float*)d_in[4];
  const float* bq = (const float*)d_in[5];
  const float* Wk = (const float*)d_in[6];
  const float* bk = (const float*)d_in[7];
  const float* Wv = (const float*)d_in[8];
  const float* bv = (const float*)d_in[9];
  const float* We = (const float*)d_in[10];
  const float* be = (const float*)d_in[11];
  const float* Ws = (const float*)d_in[12];
  const float* bs = (const float*)d_in[13];
  const int* ei_ui = (const int*)d_in[14];
  const int* ei_iu = (const int*)d_in[15];
  float* out = (float*)d_out;

  char* wp = (char*)d_ws;
  size_t used = 0;
  auto alloc = [&](size_t bytes) {
    void* p = (void*)(wp + used);
    used += (bytes + 255) & ~(size_t)255;
    return p;
  };
  const size_t NB = (size_t)NNODE * DF;
  short* xub = (short*)alloc(NB * 2);
  short* xib = (short*)alloc(NB * 2);
  short* xu1b = (short*)alloc(NB * 2);
  short* xi1b = (short*)alloc(NB * 2);
  short* qb = (short*)alloc(NB * 2);
  short* kb = (short*)alloc(NB * 2);
  short* vb = (short*)alloc(NB * 2);
  float* skipf = (float*)alloc(NB * 4);
  float* gqbuf = (float*)alloc((size_t)NNODE * 32 * 4);
  short* wt = (short*)alloc((size_t)4 * 4 * 16384 * 2);
  int* cnt = (int*)alloc((size_t)2 * (NNODE + 1) * 4);
  int* off = (int*)alloc((size_t)2 * (NNODE + 1) * 4);
  int* src_ui = (int*)alloc((size_t)NEDGE * 4);
  int* src_iu = (int*)alloc((size_t)NEDGE * 4);
  int* eid_ui = (int*)alloc((size_t)NEDGE * 4);
  int* eid_iu = (int*)alloc((size_t)NEDGE * 4);
  // permuted edge attrs last: optional if workspace allows
  size_t eac_bytes = (size_t)NEDGE * EDIM * 2;
  bool use_eac = (used + 2 * (eac_bytes + 256)) <= ws_size;
  u16* eac_ui = use_eac ? (u16*)alloc(eac_bytes) : nullptr;
  u16* eac_iu = use_eac ? (u16*)alloc(eac_bytes) : nullptr;

  const int PB = (NNODE + 127) / 128;  // 782
  int* off_ui = off;
  int* off_iu = off + (NNODE + 1);

  // pre-casts + weight transpose
  cast2_kernel<<<(int)(2 * NB / 4 + 255) / 256, 256, 0, stream>>>(
      x_user, x_item, xub, xib, (int)(NB / 4));
  transW_kernel<<<(4 * 4 * 16384) / 256, 256, 0, stream>>>(Wq, Wk, Wv, Ws, wt);

  // CSR build for both edge types
  hipMemsetAsync(cnt, 0, 2 * (NNODE + 1) * sizeof(int), stream);
  hist2_kernel<<<(2 * NEDGE + 255) / 256, 256, 0, stream>>>(
      ei_ui + NEDGE, ei_iu + NEDGE, cnt, NEDGE);
  scan_kernel<<<2, 1024, 0, stream>>>(cnt, off, NNODE);
  hipMemcpyAsync(cnt, off, 2 * (NNODE + 1) * sizeof(int), hipMemcpyDeviceToDevice, stream);
  scatter2_kernel<<<(2 * NEDGE + 255) / 256, 256, 0, stream>>>(
      ei_ui, ei_ui + NEDGE, ea_ui, ei_iu, ei_iu + NEDGE, ea_iu, cnt,
      src_ui, src_iu, eid_ui, eid_iu, eac_ui, eac_iu, NEDGE);

  auto run_conv = [&](const short* xsb, const short* xdb, int wsel, const u16* eac_t,
                      const float* ea_t, const int* eid_t, const int* src_t, const int* off_t,
                      float* outfp, short* outbp, int relu) {
    dim3 g(PB, 2);
    proj_kernel<<<g, 256, 0, stream>>>(
        xdb, xsb, NNODE,
        wt + (size_t)0 * 65536 + (size_t)wsel * 16384, bq + (size_t)wsel * DF, qb,
        wt + (size_t)3 * 65536 + (size_t)wsel * 16384, bs + (size_t)wsel * DF, skipf,
        wt + (size_t)1 * 65536 + (size_t)wsel * 16384, bk + (size_t)wsel * DF, kb,
        wt + (size_t)2 * 65536 + (size_t)wsel * 16384, bv + (size_t)wsel * DF, vb);
    gq_kernel<<<(NNODE * 32 + 255) / 256, 256, 0, stream>>>(
        qb, We + (size_t)wsel * EDIM * DF, gqbuf, NNODE);
    if (use_eac)
      edge_attn_kernel<1><<<(NNODE + 3) / 4, 256, 0, stream>>>(
          qb, kb, vb, gqbuf, We + (size_t)wsel * EDIM * DF, be + (size_t)wsel * DF,
          src_t, off_t, eac_t, nullptr, nullptr, skipf, outfp, outbp, NNODE, relu);
    else
      edge_attn_kernel<0><<<(NNODE + 3) / 4, 256, 0, stream>>>(
          qb, kb, vb, gqbuf, We + (size_t)wsel * EDIM * DF, be + (size_t)wsel * DF,
          src_t, off_t, nullptr, ea_t, eid_t, skipf, outfp, outbp, NNODE, relu);
  };

  // layer 0 (ReLU): outputs bf16 only
  run_conv(xub, xib, 0, eac_ui, ea_ui, eid_ui, src_ui, off_ui, nullptr, xi1b, 1);
  run_conv(xib, xub, 1, eac_iu, ea_iu, eid_iu, src_iu, off_iu, nullptr, xu1b, 1);
  // layer 1 (no ReLU): f32 into d_out = [x_user | x_item]
  run_conv(xu1b, xi1b, 2, eac_ui, ea_ui, eid_ui, src_ui, off_ui, out + NB, nullptr, 0);
  run_conv(xi1b, xu1b, 3, eac_iu, ea_iu, eid_iu, src_iu, off_iu, out, nullptr, 0);
}

// Round 5
// 1421.497 us; speedup vs baseline: 2.8305x; 1.5059x over previous
//
#include <hip/hip_runtime.h>
#include <hip/hip_bf16.h>
#include <math.h>

#define NNODE 100000
#define NEDGE 800000
#define DF 128
#define EDIM 32

typedef __attribute__((ext_vector_type(8))) short short8v;
typedef __attribute__((ext_vector_type(4))) float f32x4;
typedef unsigned short u16;

__device__ inline short bf16_of(float x) {
  __hip_bfloat16 h = __float2bfloat16(x);
  return *reinterpret_cast<short*>(&h);
}
__device__ inline float f_of_bf16(u16 u) {
  union { unsigned int i; float f; } c;
  c.i = ((unsigned int)u) << 16;
  return c.f;
}

// ---------------- fused pre-casts ----------------

__global__ void cast2_kernel(const float* __restrict__ a, const float* __restrict__ b,
                             short* __restrict__ ya, short* __restrict__ yb, int n4) {
  int i = blockIdx.x * blockDim.x + threadIdx.x;
  if (i < 2 * n4) {
    const float* s = (i < n4) ? a : b;
    short* y = (i < n4) ? ya : yb;
    int j = (i < n4) ? i : i - n4;
    float4 v = ((const float4*)s)[j];
    short4 o;
    o.x = bf16_of(v.x); o.y = bf16_of(v.y); o.z = bf16_of(v.z); o.w = bf16_of(v.w);
    ((short4*)y)[j] = o;
  }
}

// 4 weight families -> transposed bf16 [kind][mat][h][c]; plus We -> bf16 [conv][c][h]
__global__ void transW_kernel(const float* __restrict__ Wq, const float* __restrict__ Wk,
                              const float* __restrict__ Wv, const float* __restrict__ Ws,
                              const float* __restrict__ We, short* __restrict__ wt,
                              short* __restrict__ web) {
  int i = blockIdx.x * blockDim.x + threadIdx.x;
  if (i < 4 * 4 * 16384) {
    int kind = i >> 16;
    int rem = i & 65535;
    int m = rem >> 14, rr = rem & 16383;
    int c = rr >> 7, h = rr & 127;
    const float* W = kind == 0 ? Wq : kind == 1 ? Wk : kind == 2 ? Wv : Ws;
    wt[(size_t)kind * 65536 + m * 16384 + h * DF + c] =
        bf16_of(W[(size_t)m * 16384 + c * DF + h]);
  } else if (i < 4 * 4 * 16384 + 4 * 4096) {
    int j = i - 4 * 4 * 16384;
    web[j] = bf16_of(We[j]);  // straight cast, layout [conv][c][h]
  }
}

// ---------------- CSR build (both edge types fused) ----------------

__global__ void hist2_kernel(const int* __restrict__ d0, const int* __restrict__ d1,
                             int* __restrict__ cnt, int ne) {
  int i = blockIdx.x * blockDim.x + threadIdx.x;
  if (i < 2 * ne) {
    int t = (i >= ne);
    int e = i - t * ne;
    const int* d = t ? d1 : d0;
    atomicAdd(&cnt[t * (NNODE + 1) + d[e]], 1);
  }
}

__global__ __launch_bounds__(1024) void scan_kernel(const int* __restrict__ cntg,
                                                    int* __restrict__ offg, int n) {
  const int* cnt = cntg + blockIdx.x * (NNODE + 1);
  int* off = offg + blockIdx.x * (NNODE + 1);
  __shared__ int lds[1024];
  __shared__ int carry_s;
  int t = threadIdx.x;
  if (t == 0) carry_s = 0;
  __syncthreads();
  for (int base = 0; base < n; base += 8192) {
    int x[8];
    int s = 0;
#pragma unroll
    for (int i = 0; i < 8; ++i) {
      int idx = base + t * 8 + i;
      x[i] = (idx < n) ? cnt[idx] : 0;
      s += x[i];
    }
    lds[t] = s;
    __syncthreads();
#pragma unroll
    for (int st = 1; st < 1024; st <<= 1) {
      int v2 = (t >= st) ? lds[t - st] : 0;
      __syncthreads();
      lds[t] += v2;
      __syncthreads();
    }
    int excl = carry_s + lds[t] - s;
#pragma unroll
    for (int i = 0; i < 8; ++i) {
      int idx = base + t * 8 + i;
      if (idx < n) off[idx] = excl;
      excl += x[i];
    }
    __syncthreads();
    if (t == 0) carry_s += lds[1023];
    __syncthreads();
  }
  if (t == 0) off[n] = carry_s;
}

__global__ void scatter2_kernel(const int* __restrict__ s0, const int* __restrict__ d0,
                                const float* __restrict__ ea0,
                                const int* __restrict__ s1, const int* __restrict__ d1,
                                const float* __restrict__ ea1,
                                int* __restrict__ cur, int* __restrict__ src0c,
                                int* __restrict__ src1c, int* __restrict__ eid0c,
                                int* __restrict__ eid1c, u16* __restrict__ eac0,
                                u16* __restrict__ eac1, int ne) {
  int i = blockIdx.x * blockDim.x + threadIdx.x;
  if (i >= 2 * ne) return;
  int t = (i >= ne);
  int e = i - t * ne;
  const int* dd = t ? d1 : d0;
  const int* ss = t ? s1 : s0;
  const float* ea = t ? ea1 : ea0;
  int* sc = t ? src1c : src0c;
  int* ec = t ? eid1c : eid0c;
  u16* ac = t ? eac1 : eac0;
  int p = atomicAdd(&cur[t * (NNODE + 1) + dd[e]], 1);
  sc[p] = ss[e];
  ec[p] = e;
  if (ac) {
    const float4* r4 = (const float4*)(ea + (size_t)e * EDIM);
    u16* w = ac + (size_t)p * EDIM;
#pragma unroll
    for (int j = 0; j < 8; ++j) {
      float4 v = r4[j];
      short4 o;
      o.x = bf16_of(v.x); o.y = bf16_of(v.y); o.z = bf16_of(v.z); o.w = bf16_of(v.w);
      *(short4*)(w + j * 4) = o;
    }
  }
}

// ---------------- fused MFMA projections: q,skip,k,v in one dispatch ----------------
// operand-swapped mfma: D[h][node] -> lane stores float4/short4 along h
__global__ __launch_bounds__(256) void proj_kernel(
    const short* __restrict__ xd, const short* __restrict__ xs, int n,
    const short* __restrict__ wtq, const float* __restrict__ bq, short* __restrict__ qb,
    const short* __restrict__ wts, const float* __restrict__ bs, float* __restrict__ skipf,
    const short* __restrict__ wtk, const float* __restrict__ bk, short* __restrict__ kb,
    const short* __restrict__ wtv, const float* __restrict__ bv, short* __restrict__ vb) {
  __shared__ short Xs[128 * 128];
  int t = threadIdx.x;
  int row0 = blockIdx.x * 128;
  int job = blockIdx.y;
  const short* X = job ? xs : xd;

  // stage X tile, XOR-swizzled 16B chunks
#pragma unroll
  for (int i = 0; i < 16; ++i) {
    int idx4 = t + i * 256;
    int row = idx4 >> 5;
    int q4 = idx4 & 31;
    short4 val; val.x = val.y = val.z = val.w = 0;
    if (row0 + row < n) val = ((const short4*)(X + (size_t)(row0 + row) * DF))[q4];
    int chunk = q4 >> 1, within = (q4 & 1) * 4;
    *(short4*)&Xs[row * 128 + ((chunk ^ (row & 15)) << 3) + within] = val;
  }
  __syncthreads();

  int lane = t & 63, wave = t >> 6;
  int wm = wave >> 1, wh = wave & 1;
  int fr = lane & 15, kq = lane >> 4;

  for (int p = 0; p < 2; ++p) {
    const short* Wt = job ? (p ? wtv : wtk) : (p ? wts : wtq);
    const float* bb = job ? (p ? bv : bk) : (p ? bs : bq);
    f32x4 acc[4][4];
#pragma unroll
    for (int m = 0; m < 4; ++m)
#pragma unroll
      for (int nf = 0; nf < 4; ++nf) acc[m][nf] = (f32x4){0.f, 0.f, 0.f, 0.f};

#pragma unroll
    for (int kk = 0; kk < 4; ++kk) {
      short8v xf[4], wf[4];
      int chunk = kk * 4 + kq;
#pragma unroll
      for (int m = 0; m < 4; ++m) {
        int row = wm * 64 + m * 16 + fr;
        xf[m] = *(const short8v*)&Xs[row * 128 + ((chunk ^ (row & 15)) << 3)];
      }
#pragma unroll
      for (int nf = 0; nf < 4; ++nf) {
        int h = wh * 64 + nf * 16 + fr;
        wf[nf] = *(const short8v*)(Wt + (size_t)h * DF + kk * 32 + kq * 8);
      }
#pragma unroll
      for (int m = 0; m < 4; ++m)
#pragma unroll
        for (int nf = 0; nf < 4; ++nf)
          acc[m][nf] = __builtin_amdgcn_mfma_f32_16x16x32_bf16(wf[nf], xf[m], acc[m][nf], 0, 0, 0);
    }

    short* Yb = job ? (p ? vb : kb) : (p ? nullptr : qb);
    float* Yf = (!job && p) ? skipf : nullptr;
#pragma unroll
    for (int nf = 0; nf < 4; ++nf) {
      float4 b4 = *(const float4*)(bb + wh * 64 + nf * 16 + kq * 4);
#pragma unroll
      for (int m = 0; m < 4; ++m) {
        int node = row0 + wm * 64 + m * 16 + fr;
        if (node < n) {
          f32x4 r = acc[m][nf];
          float v0 = r[0] + b4.x, v1 = r[1] + b4.y, v2 = r[2] + b4.z, v3 = r[3] + b4.w;
          size_t o = (size_t)node * DF + wh * 64 + nf * 16 + kq * 4;
          if (Yf) {
            *(float4*)(Yf + o) = make_float4(v0, v1, v2, v3);
          } else {
            short4 s4;
            s4.x = bf16_of(v0); s4.y = bf16_of(v1); s4.z = bf16_of(v2); s4.w = bf16_of(v3);
            *(short4*)(Yb + o) = s4;
          }
        }
      }
    }
  }
}

// ---------------- gq = 0.5 * We @ q via MFMA: [n,128] @ [128,32] ----------------
__global__ __launch_bounds__(256) void gq_mfma_kernel(const short* __restrict__ qb,
                                                      const short* __restrict__ web,
                                                      float* __restrict__ gq, int n) {
  int t = threadIdx.x;
  int lane = t & 63, w = t >> 6;
  int fr = lane & 15, kq = lane >> 4;
  int row0 = blockIdx.x * 128 + w * 32;

  f32x4 acc[2][2];
#pragma unroll
  for (int mm = 0; mm < 2; ++mm)
#pragma unroll
    for (int nf = 0; nf < 2; ++nf) acc[mm][nf] = (f32x4){0.f, 0.f, 0.f, 0.f};

#pragma unroll
  for (int kk = 0; kk < 4; ++kk) {
    short8v af[2], bfr[2];
#pragma unroll
    for (int nf = 0; nf < 2; ++nf) {
      int cc = nf * 16 + fr;
      af[nf] = *(const short8v*)(web + (size_t)cc * DF + kk * 32 + kq * 8);
    }
#pragma unroll
    for (int mm = 0; mm < 2; ++mm) {
      int row = row0 + mm * 16 + fr;
      if (row < n)
        bfr[mm] = *(const short8v*)(qb + (size_t)row * DF + kk * 32 + kq * 8);
      else
        bfr[mm] = (short8v){0, 0, 0, 0, 0, 0, 0, 0};
    }
#pragma unroll
    for (int mm = 0; mm < 2; ++mm)
#pragma unroll
      for (int nf = 0; nf < 2; ++nf)
        acc[mm][nf] = __builtin_amdgcn_mfma_f32_16x16x32_bf16(af[nf], bfr[mm], acc[mm][nf], 0, 0, 0);
  }

#pragma unroll
  for (int mm = 0; mm < 2; ++mm) {
    int node = row0 + mm * 16 + fr;
    if (node < n) {
#pragma unroll
      for (int nf = 0; nf < 2; ++nf) {
        f32x4 r = acc[mm][nf];
        r = r * 0.5f;
        *(f32x4*)(gq + (size_t)node * 32 + nf * 16 + kq * 4) = r;
      }
    }
  }
}

// ---------------- fused edge attention: 1 wave / node, 8-edge batches ----------------
template <int PERM>
__global__ __launch_bounds__(256) void edge_attn_kernel(
    const short* __restrict__ qb, const short* __restrict__ kb, const short* __restrict__ vb,
    const float* __restrict__ gq, const float* __restrict__ We, const float* __restrict__ be,
    const int* __restrict__ src_csr, const int* __restrict__ off,
    const u16* __restrict__ eac, const float* __restrict__ ea, const int* __restrict__ eidc,
    const float* __restrict__ skipf, float* __restrict__ outf, short* __restrict__ outb,
    int nd, int relu) {
  int lane = threadIdx.x & 63;
  int node = blockIdx.x * 4 + (threadIdx.x >> 6);
  if (node >= nd) return;
  int c = lane & 31;
  int e0 = off[node], e1 = off[node + 1];
  size_t ob = (size_t)node * DF + 2 * lane;

  ushort2 qu = *(const ushort2*)((const u16*)qb + ob);
  float2 q01 = make_float2(f_of_bf16(qu.x), f_of_bf16(qu.y));
  float gqc = gq[node * 32 + c];
  float2 be2 = *(const float2*)(be + 2 * lane);
  float pb = q01.x * be2.x + q01.y * be2.y;
#pragma unroll
  for (int o = 32; o; o >>= 1) pb += __shfl_xor(pb, o);

  const float scale = 0.08838834764831845f;  // 128^-0.5
  float m = -INFINITY, ssum = 0.f, ag0 = 0.f, ag1 = 0.f, acce = 0.f;

  for (int j0 = e0; j0 < e1; j0 += 8) {
    int si[8];
    float av[8], a[8];
    float2 kv[8], vv[8];
#pragma unroll
    for (int i = 0; i < 8; ++i) {
      int jj = (j0 + i < e1) ? j0 + i : e1 - 1;
      si[i] = src_csr[jj];
    }
#pragma unroll
    for (int i = 0; i < 8; ++i) {
      int jj = (j0 + i < e1) ? j0 + i : e1 - 1;
      av[i] = PERM ? f_of_bf16(eac[(size_t)jj * EDIM + c])
                   : ea[(size_t)eidc[jj] * EDIM + c];
    }
#pragma unroll
    for (int i = 0; i < 8; ++i) {
      ushort2 u = *(const ushort2*)((const u16*)kb + (size_t)si[i] * DF + 2 * lane);
      kv[i] = make_float2(f_of_bf16(u.x), f_of_bf16(u.y));
    }
#pragma unroll
    for (int i = 0; i < 8; ++i) {
      ushort2 u = *(const ushort2*)((const u16*)vb + (size_t)si[i] * DF + 2 * lane);
      vv[i] = make_float2(f_of_bf16(u.x), f_of_bf16(u.y));
    }
#pragma unroll
    for (int i = 0; i < 8; ++i) {
      float p = q01.x * kv[i].x + q01.y * kv[i].y + av[i] * gqc;
#pragma unroll
      for (int o = 32; o; o >>= 1) p += __shfl_xor(p, o);
      a[i] = (j0 + i < e1) ? (p + pb) * scale : -INFINITY;
    }
    float mn = m;
#pragma unroll
    for (int i = 0; i < 8; ++i) mn = fmaxf(mn, a[i]);
    if (mn > m) {  // wave-uniform
      float f = __expf(m - mn);
      ssum *= f; ag0 *= f; ag1 *= f; acce *= f;
      m = mn;
    }
#pragma unroll
    for (int i = 0; i < 8; ++i) {
      float w = __expf(a[i] - m);
      ssum += w;
      ag0 += w * vv[i].x;
      ag1 += w * vv[i].y;
      acce += w * av[i];
    }
  }

  float2 sk = *(const float2*)(skipf + ob);
  float o0 = sk.x, o1 = sk.y;
  if (ssum > 0.f) {
    float inv = 1.f / ssum;
    float t0 = 0.f, t1 = 0.f;
#pragma unroll
    for (int cc = 0; cc < 32; ++cc) {
      float ac = __shfl(acce, cc, 64);
      float2 w2 = *(const float2*)(We + cc * DF + 2 * lane);
      t0 += ac * w2.x;
      t1 += ac * w2.y;
    }
    o0 += (ag0 + t0) * inv + be2.x;
    o1 += (ag1 + t1) * inv + be2.y;
  }
  if (relu) {
    o0 = fmaxf(o0, 0.f);
    o1 = fmaxf(o1, 0.f);
  }
  if (outf) *(float2*)(outf + ob) = make_float2(o0, o1);
  if (outb) {
    short2 s;
    s.x = bf16_of(o0);
    s.y = bf16_of(o1);
    *(short2*)(outb + ob) = s;
  }
}

// ---------------- launch ----------------

extern "C" void kernel_launch(void* const* d_in, const int* in_sizes, int n_in,
                              void* d_out, int out_size, void* d_ws, size_t ws_size,
                              hipStream_t stream) {
  const float* x_user = (const float*)d_in[0];
  const float* x_item = (const float*)d_in[1];
  const float* ea_ui = (const float*)d_in[2];
  const float* ea_iu = (const float*)d_in[3];
  const float* Wq = (const float*)d_in[4];
  const float* bq = (const float*)d_in[5];
  const float* Wk = (const float*)d_in[6];
  const float* bk = (const float*)d_in[7];
  const float* Wv = (const float*)d_in[8];
  const float* bv = (const float*)d_in[9];
  const float* We = (const float*)d_in[10];
  const float* be = (const float*)d_in[11];
  const float* Ws = (const float*)d_in[12];
  const float* bs = (const float*)d_in[13];
  const int* ei_ui = (const int*)d_in[14];
  const int* ei_iu = (const int*)d_in[15];
  float* out = (float*)d_out;

  char* wp = (char*)d_ws;
  size_t used = 0;
  auto alloc = [&](size_t bytes) {
    void* p = (void*)(wp + used);
    used += (bytes + 255) & ~(size_t)255;
    return p;
  };
  const size_t NB = (size_t)NNODE * DF;
  short* xub = (short*)alloc(NB * 2);
  short* xib = (short*)alloc(NB * 2);
  short* xu1b = (short*)alloc(NB * 2);
  short* xi1b = (short*)alloc(NB * 2);
  short* qb = (short*)alloc(NB * 2);
  short* kb = (short*)alloc(NB * 2);
  short* vb = (short*)alloc(NB * 2);
  float* skipf = (float*)alloc(NB * 4);
  float* gqbuf = (float*)alloc((size_t)NNODE * 32 * 4);
  short* wt = (short*)alloc((size_t)4 * 4 * 16384 * 2);
  short* web = (short*)alloc((size_t)4 * 4096 * 2);
  int* cnt = (int*)alloc((size_t)2 * (NNODE + 1) * 4);
  int* off = (int*)alloc((size_t)2 * (NNODE + 1) * 4);
  int* src_ui = (int*)alloc((size_t)NEDGE * 4);
  int* src_iu = (int*)alloc((size_t)NEDGE * 4);
  int* eid_ui = (int*)alloc((size_t)NEDGE * 4);
  int* eid_iu = (int*)alloc((size_t)NEDGE * 4);
  size_t eac_bytes = (size_t)NEDGE * EDIM * 2;
  bool use_eac = (used + 2 * (eac_bytes + 256)) <= ws_size;
  u16* eac_ui = use_eac ? (u16*)alloc(eac_bytes) : nullptr;
  u16* eac_iu = use_eac ? (u16*)alloc(eac_bytes) : nullptr;

  const int PB = (NNODE + 127) / 128;  // 782
  int* off_ui = off;
  int* off_iu = off + (NNODE + 1);

  cast2_kernel<<<(int)(2 * NB / 4 + 255) / 256, 256, 0, stream>>>(
      x_user, x_item, xub, xib, (int)(NB / 4));
  transW_kernel<<<(4 * 4 * 16384 + 4 * 4096 + 255) / 256, 256, 0, stream>>>(
      Wq, Wk, Wv, Ws, We, wt, web);

  hipMemsetAsync(cnt, 0, 2 * (NNODE + 1) * sizeof(int), stream);
  hist2_kernel<<<(2 * NEDGE + 255) / 256, 256, 0, stream>>>(
      ei_ui + NEDGE, ei_iu + NEDGE, cnt, NEDGE);
  scan_kernel<<<2, 1024, 0, stream>>>(cnt, off, NNODE);
  hipMemcpyAsync(cnt, off, 2 * (NNODE + 1) * sizeof(int), hipMemcpyDeviceToDevice, stream);
  scatter2_kernel<<<(2 * NEDGE + 255) / 256, 256, 0, stream>>>(
      ei_ui, ei_ui + NEDGE, ea_ui, ei_iu, ei_iu + NEDGE, ea_iu, cnt,
      src_ui, src_iu, eid_ui, eid_iu, eac_ui, eac_iu, NEDGE);

  auto run_conv = [&](const short* xsb, const short* xdb, int wsel, const u16* eac_t,
                      const float* ea_t, const int* eid_t, const int* src_t, const int* off_t,
                      float* outfp, short* outbp, int relu) {
    dim3 g(PB, 2);
    proj_kernel<<<g, 256, 0, stream>>>(
        xdb, xsb, NNODE,
        wt + (size_t)0 * 65536 + (size_t)wsel * 16384, bq + (size_t)wsel * DF, qb,
        wt + (size_t)3 * 65536 + (size_t)wsel * 16384, bs + (size_t)wsel * DF, skipf,
        wt + (size_t)1 * 65536 + (size_t)wsel * 16384, bk + (size_t)wsel * DF, kb,
        wt + (size_t)2 * 65536 + (size_t)wsel * 16384, bv + (size_t)wsel * DF, vb);
    gq_mfma_kernel<<<PB, 256, 0, stream>>>(qb, web + (size_t)wsel * 4096, gqbuf, NNODE);
    if (use_eac)
      edge_attn_kernel<1><<<(NNODE + 3) / 4, 256, 0, stream>>>(
          qb, kb, vb, gqbuf, We + (size_t)wsel * EDIM * DF, be + (size_t)wsel * DF,
          src_t, off_t, eac_t, nullptr, nullptr, skipf, outfp, outbp, NNODE, relu);
    else
      edge_attn_kernel<0><<<(NNODE + 3) / 4, 256, 0, stream>>>(
          qb, kb, vb, gqbuf, We + (size_t)wsel * EDIM * DF, be + (size_t)wsel * DF,
          src_t, off_t, nullptr, ea_t, eid_t, skipf, outfp, outbp, NNODE, relu);
  };

  // layer 0 (ReLU): outputs bf16 only
  run_conv(xub, xib, 0, eac_ui, ea_ui, eid_ui, src_ui, off_ui, nullptr, xi1b, 1);
  run_conv(xib, xub, 1, eac_iu, ea_iu, eid_iu, src_iu, off_iu, nullptr, xu1b, 1);
  // layer 1 (no ReLU): f32 into d_out = [x_user | x_item]
  run_conv(xu1b, xi1b, 2, eac_ui, ea_ui, eid_ui, src_ui, off_ui, out + NB, nullptr, 0);
  run_conv(xi1b, xu1b, 3, eac_iu, ea_iu, eid_iu, src_iu, off_iu, out, nullptr, 0);
}

// Round 6
// 1332.791 us; speedup vs baseline: 3.0189x; 1.0666x over previous
//
#include <hip/hip_runtime.h>
#include <hip/hip_bf16.h>
#include <math.h>

#define NNODE 100000
#define NEDGE 800000
#define DF 128
#define EDIM 32

typedef __attribute__((ext_vector_type(8))) short short8v;
typedef __attribute__((ext_vector_type(8))) unsigned short ushort8v;
typedef __attribute__((ext_vector_type(4))) float f32x4;
typedef unsigned short u16;

__device__ inline short bf16_of(float x) {
  __hip_bfloat16 h = __float2bfloat16(x);
  return *reinterpret_cast<short*>(&h);
}
__device__ inline float f_of_bf16(u16 u) {
  union { unsigned int i; float f; } c;
  c.i = ((unsigned int)u) << 16;
  return c.f;
}

// ---------------- fused pre-casts ----------------

__global__ void cast2_kernel(const float* __restrict__ a, const float* __restrict__ b,
                             short* __restrict__ ya, short* __restrict__ yb, int n4) {
  int i = blockIdx.x * blockDim.x + threadIdx.x;
  if (i < 2 * n4) {
    const float* s = (i < n4) ? a : b;
    short* y = (i < n4) ? ya : yb;
    int j = (i < n4) ? i : i - n4;
    float4 v = ((const float4*)s)[j];
    short4 o;
    o.x = bf16_of(v.x); o.y = bf16_of(v.y); o.z = bf16_of(v.z); o.w = bf16_of(v.w);
    ((short4*)y)[j] = o;
  }
}

// wt: [kind][mat][h][c] bf16 (transposed); web: [conv][c][h]; webT: [conv][h][c]
__global__ void transW_kernel(const float* __restrict__ Wq, const float* __restrict__ Wk,
                              const float* __restrict__ Wv, const float* __restrict__ Ws,
                              const float* __restrict__ We, short* __restrict__ wt,
                              short* __restrict__ web, short* __restrict__ webT) {
  int i = blockIdx.x * blockDim.x + threadIdx.x;
  if (i < 4 * 4 * 16384) {
    int kind = i >> 16;
    int rem = i & 65535;
    int m = rem >> 14, rr = rem & 16383;
    int c = rr >> 7, h = rr & 127;
    const float* W = kind == 0 ? Wq : kind == 1 ? Wk : kind == 2 ? Wv : Ws;
    wt[(size_t)kind * 65536 + m * 16384 + h * DF + c] =
        bf16_of(W[(size_t)m * 16384 + c * DF + h]);
  } else if (i < 4 * 4 * 16384 + 4 * 4096) {
    int j = i - 4 * 4 * 16384;
    web[j] = bf16_of(We[j]);  // [conv][c][h]
  } else if (i < 4 * 4 * 16384 + 2 * 4 * 4096) {
    int j = i - (4 * 4 * 16384 + 4 * 4096);
    int conv = j >> 12, rr = j & 4095;
    int h = rr >> 5, c = rr & 31;
    webT[j] = bf16_of(We[(size_t)conv * 4096 + c * DF + h]);  // [conv][h][c]
  }
}

// ---------------- CSR build (both edge types fused) ----------------

__global__ void hist2_kernel(const int* __restrict__ d0, const int* __restrict__ d1,
                             int* __restrict__ cnt, int ne) {
  int i = blockIdx.x * blockDim.x + threadIdx.x;
  if (i < 2 * ne) {
    int t = (i >= ne);
    int e = i - t * ne;
    const int* d = t ? d1 : d0;
    atomicAdd(&cnt[t * (NNODE + 1) + d[e]], 1);
  }
}

__global__ __launch_bounds__(1024) void scan_kernel(const int* __restrict__ cntg,
                                                    int* __restrict__ offg, int n) {
  const int* cnt = cntg + blockIdx.x * (NNODE + 1);
  int* off = offg + blockIdx.x * (NNODE + 1);
  __shared__ int lds[1024];
  __shared__ int carry_s;
  int t = threadIdx.x;
  if (t == 0) carry_s = 0;
  __syncthreads();
  for (int base = 0; base < n; base += 8192) {
    int x[8];
    int s = 0;
#pragma unroll
    for (int i = 0; i < 8; ++i) {
      int idx = base + t * 8 + i;
      x[i] = (idx < n) ? cnt[idx] : 0;
      s += x[i];
    }
    lds[t] = s;
    __syncthreads();
#pragma unroll
    for (int st = 1; st < 1024; st <<= 1) {
      int v2 = (t >= st) ? lds[t - st] : 0;
      __syncthreads();
      lds[t] += v2;
      __syncthreads();
    }
    int excl = carry_s + lds[t] - s;
#pragma unroll
    for (int i = 0; i < 8; ++i) {
      int idx = base + t * 8 + i;
      if (idx < n) off[idx] = excl;
      excl += x[i];
    }
    __syncthreads();
    if (t == 0) carry_s += lds[1023];
    __syncthreads();
  }
  if (t == 0) off[n] = carry_s;
}

__global__ void scatter2_kernel(const int* __restrict__ s0, const int* __restrict__ d0,
                                const float* __restrict__ ea0,
                                const int* __restrict__ s1, const int* __restrict__ d1,
                                const float* __restrict__ ea1,
                                int* __restrict__ cur, int* __restrict__ src0c,
                                int* __restrict__ src1c, int* __restrict__ eid0c,
                                int* __restrict__ eid1c, u16* __restrict__ eac0,
                                u16* __restrict__ eac1, int ne) {
  int i = blockIdx.x * blockDim.x + threadIdx.x;
  if (i >= 2 * ne) return;
  int t = (i >= ne);
  int e = i - t * ne;
  const int* dd = t ? d1 : d0;
  const int* ss = t ? s1 : s0;
  const float* ea = t ? ea1 : ea0;
  int* sc = t ? src1c : src0c;
  int* ec = t ? eid1c : eid0c;
  u16* ac = t ? eac1 : eac0;
  int p = atomicAdd(&cur[t * (NNODE + 1) + dd[e]], 1);
  sc[p] = ss[e];
  ec[p] = e;
  if (ac) {
    const float4* r4 = (const float4*)(ea + (size_t)e * EDIM);
    u16* w = ac + (size_t)p * EDIM;
#pragma unroll
    for (int j = 0; j < 8; ++j) {
      float4 v = r4[j];
      short4 o;
      o.x = bf16_of(v.x); o.y = bf16_of(v.y); o.z = bf16_of(v.z); o.w = bf16_of(v.w);
      *(short4*)(w + j * 4) = o;
    }
  }
}

// ---------------- fused MFMA projections: q,skip,k,v in one dispatch ----------------
__global__ __launch_bounds__(256) void proj_kernel(
    const short* __restrict__ xd, const short* __restrict__ xs, int n,
    const short* __restrict__ wtq, const float* __restrict__ bq, short* __restrict__ qb,
    const short* __restrict__ wts, const float* __restrict__ bs, float* __restrict__ skipf,
    const short* __restrict__ wtk, const float* __restrict__ bk, short* __restrict__ kb,
    const short* __restrict__ wtv, const float* __restrict__ bv, short* __restrict__ vb) {
  __shared__ short Xs[128 * 128];
  int t = threadIdx.x;
  int row0 = blockIdx.x * 128;
  int job = blockIdx.y;
  const short* X = job ? xs : xd;

#pragma unroll
  for (int i = 0; i < 16; ++i) {
    int idx4 = t + i * 256;
    int row = idx4 >> 5;
    int q4 = idx4 & 31;
    short4 val; val.x = val.y = val.z = val.w = 0;
    if (row0 + row < n) val = ((const short4*)(X + (size_t)(row0 + row) * DF))[q4];
    int chunk = q4 >> 1, within = (q4 & 1) * 4;
    *(short4*)&Xs[row * 128 + ((chunk ^ (row & 15)) << 3) + within] = val;
  }
  __syncthreads();

  int lane = t & 63, wave = t >> 6;
  int wm = wave >> 1, wh = wave & 1;
  int fr = lane & 15, kq = lane >> 4;

  for (int p = 0; p < 2; ++p) {
    const short* Wt = job ? (p ? wtv : wtk) : (p ? wts : wtq);
    const float* bb = job ? (p ? bv : bk) : (p ? bs : bq);
    f32x4 acc[4][4];
#pragma unroll
    for (int m = 0; m < 4; ++m)
#pragma unroll
      for (int nf = 0; nf < 4; ++nf) acc[m][nf] = (f32x4){0.f, 0.f, 0.f, 0.f};

#pragma unroll
    for (int kk = 0; kk < 4; ++kk) {
      short8v xf[4], wf[4];
      int chunk = kk * 4 + kq;
#pragma unroll
      for (int m = 0; m < 4; ++m) {
        int row = wm * 64 + m * 16 + fr;
        xf[m] = *(const short8v*)&Xs[row * 128 + ((chunk ^ (row & 15)) << 3)];
      }
#pragma unroll
      for (int nf = 0; nf < 4; ++nf) {
        int h = wh * 64 + nf * 16 + fr;
        wf[nf] = *(const short8v*)(Wt + (size_t)h * DF + kk * 32 + kq * 8);
      }
#pragma unroll
      for (int m = 0; m < 4; ++m)
#pragma unroll
        for (int nf = 0; nf < 4; ++nf)
          acc[m][nf] = __builtin_amdgcn_mfma_f32_16x16x32_bf16(wf[nf], xf[m], acc[m][nf], 0, 0, 0);
    }

    short* Yb = job ? (p ? vb : kb) : (p ? nullptr : qb);
    float* Yf = (!job && p) ? skipf : nullptr;
#pragma unroll
    for (int nf = 0; nf < 4; ++nf) {
      float4 b4 = *(const float4*)(bb + wh * 64 + nf * 16 + kq * 4);
#pragma unroll
      for (int m = 0; m < 4; ++m) {
        int node = row0 + wm * 64 + m * 16 + fr;
        if (node < n) {
          f32x4 r = acc[m][nf];
          float v0 = r[0] + b4.x, v1 = r[1] + b4.y, v2 = r[2] + b4.z, v3 = r[3] + b4.w;
          size_t o = (size_t)node * DF + wh * 64 + nf * 16 + kq * 4;
          if (Yf) {
            *(float4*)(Yf + o) = make_float4(v0, v1, v2, v3);
          } else {
            short4 s4;
            s4.x = bf16_of(v0); s4.y = bf16_of(v1); s4.z = bf16_of(v2); s4.w = bf16_of(v3);
            *(short4*)(Yb + o) = s4;
          }
        }
      }
    }
  }
}

// ---------------- gq = We @ q via MFMA: [n,128] @ [128,32] (unscaled) ----------------
__global__ __launch_bounds__(256) void gq_mfma_kernel(const short* __restrict__ qb,
                                                      const short* __restrict__ web,
                                                      float* __restrict__ gq, int n) {
  int t = threadIdx.x;
  int lane = t & 63, w = t >> 6;
  int fr = lane & 15, kq = lane >> 4;
  int row0 = blockIdx.x * 128 + w * 32;

  f32x4 acc[2][2];
#pragma unroll
  for (int mm = 0; mm < 2; ++mm)
#pragma unroll
    for (int nf = 0; nf < 2; ++nf) acc[mm][nf] = (f32x4){0.f, 0.f, 0.f, 0.f};

#pragma unroll
  for (int kk = 0; kk < 4; ++kk) {
    short8v af[2], bfr[2];
#pragma unroll
    for (int nf = 0; nf < 2; ++nf) {
      int cc = nf * 16 + fr;
      af[nf] = *(const short8v*)(web + (size_t)cc * DF + kk * 32 + kq * 8);
    }
#pragma unroll
    for (int mm = 0; mm < 2; ++mm) {
      int row = row0 + mm * 16 + fr;
      if (row < n)
        bfr[mm] = *(const short8v*)(qb + (size_t)row * DF + kk * 32 + kq * 8);
      else
        bfr[mm] = (short8v){0, 0, 0, 0, 0, 0, 0, 0};
    }
#pragma unroll
    for (int mm = 0; mm < 2; ++mm)
#pragma unroll
      for (int nf = 0; nf < 2; ++nf)
        acc[mm][nf] = __builtin_amdgcn_mfma_f32_16x16x32_bf16(af[nf], bfr[mm], acc[mm][nf], 0, 0, 0);
  }

#pragma unroll
  for (int mm = 0; mm < 2; ++mm) {
    int node = row0 + mm * 16 + fr;
    if (node < n) {
#pragma unroll
      for (int nf = 0; nf < 2; ++nf) {
        *(f32x4*)(gq + (size_t)node * 32 + nf * 16 + kq * 4) = acc[mm][nf];
      }
    }
  }
}

// ---------------- fused edge attention: 1 wave/node, 4 edges via 16-lane groups ----------------
// outputs: tmpo = skip + agg/ssum + be (f32); accb = (sum w*ea)/ssum (bf16 [n,32])
template <int PERM>
__global__ __launch_bounds__(256) void edge_attn_kernel(
    const short* __restrict__ qb, const short* __restrict__ kb, const short* __restrict__ vb,
    const float* __restrict__ gq, const float* __restrict__ be,
    const int* __restrict__ src_csr, const int* __restrict__ off,
    const u16* __restrict__ eac, const float* __restrict__ ea, const int* __restrict__ eidc,
    const float* __restrict__ skipf, float* __restrict__ tmpo, short* __restrict__ accb,
    int nd) {
  int lane = threadIdx.x & 63;
  int node = blockIdx.x * 4 + (threadIdx.x >> 6);
  if (node >= nd) return;
  int grp = lane >> 4, sl = lane & 15;
  int e0 = off[node], e1 = off[node + 1];

  // q dims sl*8..+8 (dup across the 4 groups)
  ushort8v qu = *(const ushort8v*)((const u16*)qb + (size_t)node * DF + sl * 8);
  float qd[8];
#pragma unroll
  for (int d = 0; d < 8; ++d) qd[d] = f_of_bf16(qu[d]);
  float bed[8];
  {
    float4 b0 = *(const float4*)(be + sl * 8);
    float4 b1 = *(const float4*)(be + sl * 8 + 4);
    bed[0] = b0.x; bed[1] = b0.y; bed[2] = b0.z; bed[3] = b0.w;
    bed[4] = b1.x; bed[5] = b1.y; bed[6] = b1.z; bed[7] = b1.w;
  }
  float pb = 0.f;
#pragma unroll
  for (int d = 0; d < 8; ++d) pb += qd[d] * bed[d];
#pragma unroll
  for (int o = 1; o <= 8; o <<= 1) pb += __shfl_xor(pb, o);

  float2 gq2 = *(const float2*)(gq + (size_t)node * 32 + sl * 2);

  const float scale = 0.08838834764831845f;  // 128^-0.5
  float m = -INFINITY, ssum = 0.f, an0 = 0.f, an1 = 0.f;
  float agg[8];
#pragma unroll
  for (int d = 0; d < 8; ++d) agg[d] = 0.f;

  for (int j0 = e0; j0 < e1; j0 += 4) {
    int j = j0 + grp;
    int jc = (j < e1) ? j : e1 - 1;
    int si = src_csr[jc];
    float ea0, ea1;
    if (PERM) {
      ushort2 eu = *(const ushort2*)(eac + (size_t)jc * EDIM + sl * 2);
      ea0 = f_of_bf16(eu.x);
      ea1 = f_of_bf16(eu.y);
    } else {
      float2 ef = *(const float2*)(ea + (size_t)eidc[jc] * EDIM + sl * 2);
      ea0 = ef.x;
      ea1 = ef.y;
    }
    ushort8v ku = *(const ushort8v*)((const u16*)kb + (size_t)si * DF + sl * 8);
    ushort8v vu = *(const ushort8v*)((const u16*)vb + (size_t)si * DF + sl * 8);
    float p = ea0 * gq2.x + ea1 * gq2.y;
#pragma unroll
    for (int d = 0; d < 8; ++d) p += qd[d] * f_of_bf16(ku[d]);
#pragma unroll
    for (int o = 1; o <= 8; o <<= 1) p += __shfl_xor(p, o);  // reduce within 16-lane group
    float a = (j < e1) ? (p + pb) * scale : -INFINITY;
    float amax = fmaxf(a, __shfl_xor(a, 16));
    amax = fmaxf(amax, __shfl_xor(amax, 32));  // wave-wide batch max
    float mn = fmaxf(m, amax);
    if (mn > m) {  // wave-uniform
      float f = __expf(m - mn);
      ssum *= f; an0 *= f; an1 *= f;
#pragma unroll
      for (int d = 0; d < 8; ++d) agg[d] *= f;
      m = mn;
    }
    float w = __expf(a - m);  // 0 for invalid lanes (a = -inf)
    ssum += w;
    an0 += w * ea0;
    an1 += w * ea1;
#pragma unroll
    for (int d = 0; d < 8; ++d) agg[d] += w * f_of_bf16(vu[d]);
  }

  // cross-group reduction (once per node)
  ssum += __shfl_xor(ssum, 16); ssum += __shfl_xor(ssum, 32);
  an0 += __shfl_xor(an0, 16); an0 += __shfl_xor(an0, 32);
  an1 += __shfl_xor(an1, 16); an1 += __shfl_xor(an1, 32);
#pragma unroll
  for (int d = 0; d < 8; ++d) {
    agg[d] += __shfl_xor(agg[d], 16);
    agg[d] += __shfl_xor(agg[d], 32);
  }

  if (grp == 0) {
    float inv = (ssum > 0.f) ? 1.f / ssum : 0.f;
    short2 a2;
    a2.x = bf16_of(an0 * inv);
    a2.y = bf16_of(an1 * inv);
    *(short2*)(accb + (size_t)node * 32 + sl * 2) = a2;
    size_t ro = (size_t)node * DF + sl * 8;
    float4 s0 = *(const float4*)(skipf + ro);
    float4 s1 = *(const float4*)(skipf + ro + 4);
    float sk[8] = {s0.x, s0.y, s0.z, s0.w, s1.x, s1.y, s1.z, s1.w};
    float o[8];
#pragma unroll
    for (int d = 0; d < 8; ++d)
      o[d] = sk[d] + ((ssum > 0.f) ? agg[d] * inv + bed[d] : 0.f);
    *(float4*)(tmpo + ro) = make_float4(o[0], o[1], o[2], o[3]);
    *(float4*)(tmpo + ro + 4) = make_float4(o[4], o[5], o[6], o[7]);
  }
}

// ---------------- post-pass: out = [relu](tmpo + accn @ We) ----------------
__global__ __launch_bounds__(256) void accw_kernel(
    const float* __restrict__ tmpo, const short* __restrict__ accb,
    const short* __restrict__ webT, float* __restrict__ outf, short* __restrict__ outb,
    int n, int relu) {
  int t = threadIdx.x;
  int lane = t & 63, w = t >> 6;
  int fr = lane & 15, kq = lane >> 4;
  int row0 = blockIdx.x * 128 + w * 32;

  short8v af[8];
#pragma unroll
  for (int nf = 0; nf < 8; ++nf)
    af[nf] = *(const short8v*)(webT + (size_t)(nf * 16 + fr) * 32 + kq * 8);

#pragma unroll
  for (int mm = 0; mm < 2; ++mm) {
    int row = row0 + mm * 16 + fr;
    short8v b;
    if (row < n)
      b = *(const short8v*)(accb + (size_t)row * 32 + kq * 8);
    else
      b = (short8v){0, 0, 0, 0, 0, 0, 0, 0};
#pragma unroll
    for (int nf = 0; nf < 8; ++nf) {
      f32x4 acc = (f32x4){0.f, 0.f, 0.f, 0.f};
      acc = __builtin_amdgcn_mfma_f32_16x16x32_bf16(af[nf], b, acc, 0, 0, 0);
      if (row < n) {
        size_t o = (size_t)row * DF + nf * 16 + kq * 4;
        float4 pre = *(const float4*)(tmpo + o);
        float r0 = pre.x + acc[0], r1 = pre.y + acc[1];
        float r2 = pre.z + acc[2], r3 = pre.w + acc[3];
        if (relu) {
          r0 = fmaxf(r0, 0.f); r1 = fmaxf(r1, 0.f);
          r2 = fmaxf(r2, 0.f); r3 = fmaxf(r3, 0.f);
        }
        if (outf) *(float4*)(outf + o) = make_float4(r0, r1, r2, r3);
        if (outb) {
          short4 s4;
          s4.x = bf16_of(r0); s4.y = bf16_of(r1); s4.z = bf16_of(r2); s4.w = bf16_of(r3);
          *(short4*)(outb + o) = s4;
        }
      }
    }
  }
}

// ---------------- launch ----------------

extern "C" void kernel_launch(void* const* d_in, const int* in_sizes, int n_in,
                              void* d_out, int out_size, void* d_ws, size_t ws_size,
                              hipStream_t stream) {
  const float* x_user = (const float*)d_in[0];
  const float* x_item = (const float*)d_in[1];
  const float* ea_ui = (const float*)d_in[2];
  const float* ea_iu = (const float*)d_in[3];
  const float* Wq = (const float*)d_in[4];
  const float* bq = (const float*)d_in[5];
  const float* Wk = (const float*)d_in[6];
  const float* bk = (const float*)d_in[7];
  const float* Wv = (const float*)d_in[8];
  const float* bv = (const float*)d_in[9];
  const float* We = (const float*)d_in[10];
  const float* be = (const float*)d_in[11];
  const float* Ws = (const float*)d_in[12];
  const float* bs = (const float*)d_in[13];
  const int* ei_ui = (const int*)d_in[14];
  const int* ei_iu = (const int*)d_in[15];
  float* out = (float*)d_out;

  char* wp = (char*)d_ws;
  size_t used = 0;
  auto alloc = [&](size_t bytes) {
    void* p = (void*)(wp + used);
    used += (bytes + 255) & ~(size_t)255;
    return p;
  };
  const size_t NB = (size_t)NNODE * DF;
  short* xub = (short*)alloc(NB * 2);
  short* xib = (short*)alloc(NB * 2);
  short* xu1b = (short*)alloc(NB * 2);
  short* xi1b = (short*)alloc(NB * 2);
  short* qb = (short*)alloc(NB * 2);
  short* kb = (short*)alloc(NB * 2);
  short* vb = (short*)alloc(NB * 2);
  float* skipf = (float*)alloc(NB * 4);
  float* tmpo = (float*)alloc(NB * 4);
  float* gqbuf = (float*)alloc((size_t)NNODE * 32 * 4);
  short* accb = (short*)alloc((size_t)NNODE * 32 * 2);
  short* wt = (short*)alloc((size_t)4 * 4 * 16384 * 2);
  short* web = (short*)alloc((size_t)4 * 4096 * 2);
  short* webT = (short*)alloc((size_t)4 * 4096 * 2);
  int* cnt = (int*)alloc((size_t)2 * (NNODE + 1) * 4);
  int* off = (int*)alloc((size_t)2 * (NNODE + 1) * 4);
  int* src_ui = (int*)alloc((size_t)NEDGE * 4);
  int* src_iu = (int*)alloc((size_t)NEDGE * 4);
  int* eid_ui = (int*)alloc((size_t)NEDGE * 4);
  int* eid_iu = (int*)alloc((size_t)NEDGE * 4);
  size_t eac_bytes = (size_t)NEDGE * EDIM * 2;
  bool use_eac = (used + 2 * (eac_bytes + 256)) <= ws_size;
  u16* eac_ui = use_eac ? (u16*)alloc(eac_bytes) : nullptr;
  u16* eac_iu = use_eac ? (u16*)alloc(eac_bytes) : nullptr;

  const int PB = (NNODE + 127) / 128;  // 782
  int* off_ui = off;
  int* off_iu = off + (NNODE + 1);

  cast2_kernel<<<(int)(2 * NB / 4 + 255) / 256, 256, 0, stream>>>(
      x_user, x_item, xub, xib, (int)(NB / 4));
  transW_kernel<<<(4 * 4 * 16384 + 2 * 4 * 4096 + 255) / 256, 256, 0, stream>>>(
      Wq, Wk, Wv, Ws, We, wt, web, webT);

  hipMemsetAsync(cnt, 0, 2 * (NNODE + 1) * sizeof(int), stream);
  hist2_kernel<<<(2 * NEDGE + 255) / 256, 256, 0, stream>>>(
      ei_ui + NEDGE, ei_iu + NEDGE, cnt, NEDGE);
  scan_kernel<<<2, 1024, 0, stream>>>(cnt, off, NNODE);
  hipMemcpyAsync(cnt, off, 2 * (NNODE + 1) * sizeof(int), hipMemcpyDeviceToDevice, stream);
  scatter2_kernel<<<(2 * NEDGE + 255) / 256, 256, 0, stream>>>(
      ei_ui, ei_ui + NEDGE, ea_ui, ei_iu, ei_iu + NEDGE, ea_iu, cnt,
      src_ui, src_iu, eid_ui, eid_iu, eac_ui, eac_iu, NEDGE);

  auto run_conv = [&](const short* xsb, const short* xdb, int wsel, const u16* eac_t,
                      const float* ea_t, const int* eid_t, const int* src_t, const int* off_t,
                      float* outfp, short* outbp, int relu) {
    dim3 g(PB, 2);
    proj_kernel<<<g, 256, 0, stream>>>(
        xdb, xsb, NNODE,
        wt + (size_t)0 * 65536 + (size_t)wsel * 16384, bq + (size_t)wsel * DF, qb,
        wt + (size_t)3 * 65536 + (size_t)wsel * 16384, bs + (size_t)wsel * DF, skipf,
        wt + (size_t)1 * 65536 + (size_t)wsel * 16384, bk + (size_t)wsel * DF, kb,
        wt + (size_t)2 * 65536 + (size_t)wsel * 16384, bv + (size_t)wsel * DF, vb);
    gq_mfma_kernel<<<PB, 256, 0, stream>>>(qb, web + (size_t)wsel * 4096, gqbuf, NNODE);
    if (use_eac)
      edge_attn_kernel<1><<<(NNODE + 3) / 4, 256, 0, stream>>>(
          qb, kb, vb, gqbuf, be + (size_t)wsel * DF,
          src_t, off_t, eac_t, nullptr, nullptr, skipf, tmpo, accb, NNODE);
    else
      edge_attn_kernel<0><<<(NNODE + 3) / 4, 256, 0, stream>>>(
          qb, kb, vb, gqbuf, be + (size_t)wsel * DF,
          src_t, off_t, nullptr, ea_t, eid_t, skipf, tmpo, accb, NNODE);
    accw_kernel<<<PB, 256, 0, stream>>>(
        tmpo, accb, webT + (size_t)wsel * 4096, outfp, outbp, NNODE, relu);
  };

  // layer 0 (ReLU): outputs bf16 only
  run_conv(xub, xib, 0, eac_ui, ea_ui, eid_ui, src_ui, off_ui, nullptr, xi1b, 1);
  run_conv(xib, xub, 1, eac_iu, ea_iu, eid_iu, src_iu, off_iu, nullptr, xu1b, 1);
  // layer 1 (no ReLU): f32 into d_out = [x_user | x_item]
  run_conv(xu1b, xi1b, 2, eac_ui, ea_ui, eid_ui, src_ui, off_ui, out + NB, nullptr, 0);
  run_conv(xi1b, xu1b, 3, eac_iu, ea_iu, eid_iu, src_iu, off_iu, out, nullptr, 0);
}

// Round 7
// 1165.046 us; speedup vs baseline: 3.4535x; 1.1440x over previous
//
#include <hip/hip_runtime.h>
#include <hip/hip_bf16.h>
#include <math.h>

#define NNODE 100000
#define NEDGE 800000
#define DF 128
#define EDIM 32

typedef __attribute__((ext_vector_type(8))) short short8v;
typedef __attribute__((ext_vector_type(8))) unsigned short ushort8v;
typedef __attribute__((ext_vector_type(4))) float f32x4;
typedef unsigned short u16;

__device__ inline short bf16_of(float x) {
  __hip_bfloat16 h = __float2bfloat16(x);
  return *reinterpret_cast<short*>(&h);
}
__device__ inline float f_of_bf16(u16 u) {
  union { unsigned int i; float f; } c;
  c.i = ((unsigned int)u) << 16;
  return c.f;
}

// ---------------- fused pre-casts ----------------

__global__ void cast2_kernel(const float* __restrict__ a, const float* __restrict__ b,
                             short* __restrict__ ya, short* __restrict__ yb, int n4) {
  int i = blockIdx.x * blockDim.x + threadIdx.x;
  if (i < 2 * n4) {
    const float* s = (i < n4) ? a : b;
    short* y = (i < n4) ? ya : yb;
    int j = (i < n4) ? i : i - n4;
    float4 v = ((const float4*)s)[j];
    short4 o;
    o.x = bf16_of(v.x); o.y = bf16_of(v.y); o.z = bf16_of(v.z); o.w = bf16_of(v.w);
    ((short4*)y)[j] = o;
  }
}

// wt: [kind][mat][h][c] bf16 (transposed); web: [conv][c][h]; webT: [conv][h][c]
__global__ void transW_kernel(const float* __restrict__ Wq, const float* __restrict__ Wk,
                              const float* __restrict__ Wv, const float* __restrict__ Ws,
                              const float* __restrict__ We, short* __restrict__ wt,
                              short* __restrict__ web, short* __restrict__ webT) {
  int i = blockIdx.x * blockDim.x + threadIdx.x;
  if (i < 4 * 4 * 16384) {
    int kind = i >> 16;
    int rem = i & 65535;
    int m = rem >> 14, rr = rem & 16383;
    int c = rr >> 7, h = rr & 127;
    const float* W = kind == 0 ? Wq : kind == 1 ? Wk : kind == 2 ? Wv : Ws;
    wt[(size_t)kind * 65536 + m * 16384 + h * DF + c] =
        bf16_of(W[(size_t)m * 16384 + c * DF + h]);
  } else if (i < 4 * 4 * 16384 + 4 * 4096) {
    int j = i - 4 * 4 * 16384;
    web[j] = bf16_of(We[j]);  // [conv][c][h]
  } else if (i < 4 * 4 * 16384 + 2 * 4 * 4096) {
    int j = i - (4 * 4 * 16384 + 4 * 4096);
    int conv = j >> 12, rr = j & 4095;
    int h = rr >> 5, c = rr & 31;
    webT[j] = bf16_of(We[(size_t)conv * 4096 + c * DF + h]);  // [conv][h][c]
  }
}

// ---------------- CSR build (both edge types fused) ----------------

__global__ void hist2_kernel(const int* __restrict__ d0, const int* __restrict__ d1,
                             int* __restrict__ cnt, int ne) {
  int i = blockIdx.x * blockDim.x + threadIdx.x;
  if (i < 2 * ne) {
    int t = (i >= ne);
    int e = i - t * ne;
    const int* d = t ? d1 : d0;
    atomicAdd(&cnt[t * (NNODE + 1) + d[e]], 1);
  }
}

__global__ __launch_bounds__(1024) void scan_kernel(const int* __restrict__ cntg,
                                                    int* __restrict__ offg, int n) {
  const int* cnt = cntg + blockIdx.x * (NNODE + 1);
  int* off = offg + blockIdx.x * (NNODE + 1);
  __shared__ int lds[1024];
  __shared__ int carry_s;
  int t = threadIdx.x;
  if (t == 0) carry_s = 0;
  __syncthreads();
  for (int base = 0; base < n; base += 8192) {
    int x[8];
    int s = 0;
#pragma unroll
    for (int i = 0; i < 8; ++i) {
      int idx = base + t * 8 + i;
      x[i] = (idx < n) ? cnt[idx] : 0;
      s += x[i];
    }
    lds[t] = s;
    __syncthreads();
#pragma unroll
    for (int st = 1; st < 1024; st <<= 1) {
      int v2 = (t >= st) ? lds[t - st] : 0;
      __syncthreads();
      lds[t] += v2;
      __syncthreads();
    }
    int excl = carry_s + lds[t] - s;
#pragma unroll
    for (int i = 0; i < 8; ++i) {
      int idx = base + t * 8 + i;
      if (idx < n) off[idx] = excl;
      excl += x[i];
    }
    __syncthreads();
    if (t == 0) carry_s += lds[1023];
    __syncthreads();
  }
  if (t == 0) off[n] = carry_s;
}

__global__ void scatter2_kernel(const int* __restrict__ s0, const int* __restrict__ d0,
                                const float* __restrict__ ea0,
                                const int* __restrict__ s1, const int* __restrict__ d1,
                                const float* __restrict__ ea1,
                                int* __restrict__ cur, int* __restrict__ src0c,
                                int* __restrict__ src1c, int* __restrict__ eid0c,
                                int* __restrict__ eid1c, u16* __restrict__ eac0,
                                u16* __restrict__ eac1, int ne) {
  int i = blockIdx.x * blockDim.x + threadIdx.x;
  if (i >= 2 * ne) return;
  int t = (i >= ne);
  int e = i - t * ne;
  const int* dd = t ? d1 : d0;
  const int* ss = t ? s1 : s0;
  const float* ea = t ? ea1 : ea0;
  int* sc = t ? src1c : src0c;
  int* ec = t ? eid1c : eid0c;
  u16* ac = t ? eac1 : eac0;
  int p = atomicAdd(&cur[t * (NNODE + 1) + dd[e]], 1);
  sc[p] = ss[e];
  if (ec) ec[p] = e;
  if (ac) {
    const float4* r4 = (const float4*)(ea + (size_t)e * EDIM);
    u16* w = ac + (size_t)p * EDIM;
#pragma unroll
    for (int j = 0; j < 8; ++j) {
      float4 v = r4[j];
      short4 o;
      o.x = bf16_of(v.x); o.y = bf16_of(v.y); o.z = bf16_of(v.z); o.w = bf16_of(v.w);
      *(short4*)(w + j * 4) = o;
    }
  }
}

// ---------------- fused MFMA projections: q,skip,k,v in one dispatch ----------------
// k and v interleave into kvb rows of 256 (k at +0, v at +128)
__global__ __launch_bounds__(256) void proj_kernel(
    const short* __restrict__ xd, const short* __restrict__ xs, int n,
    const short* __restrict__ wtq, const float* __restrict__ bq, short* __restrict__ qb,
    const short* __restrict__ wts, const float* __restrict__ bs, float* __restrict__ skipf,
    const short* __restrict__ wtk, const float* __restrict__ bk,
    const short* __restrict__ wtv, const float* __restrict__ bv, short* __restrict__ kvb) {
  __shared__ short Xs[128 * 128];
  int t = threadIdx.x;
  int row0 = blockIdx.x * 128;
  int job = blockIdx.y;
  const short* X = job ? xs : xd;

  // stage X tile, 16B loads, XOR-swizzled 16B chunks
#pragma unroll
  for (int i = 0; i < 8; ++i) {
    int idx8 = t + i * 256;
    int row = idx8 >> 4;  // 16 chunks of 8 shorts per row
    int q8 = idx8 & 15;
    short8v val = (short8v){0, 0, 0, 0, 0, 0, 0, 0};
    if (row0 + row < n) val = ((const short8v*)(X + (size_t)(row0 + row) * DF))[q8];
    *(short8v*)&Xs[row * 128 + ((q8 ^ (row & 15)) << 3)] = val;
  }
  __syncthreads();

  int lane = t & 63, wave = t >> 6;
  int wm = wave >> 1, wh = wave & 1;
  int fr = lane & 15, kq = lane >> 4;

  for (int p = 0; p < 2; ++p) {
    const short* Wt = job ? (p ? wtv : wtk) : (p ? wts : wtq);
    const float* bb = job ? (p ? bv : bk) : (p ? bs : bq);
    f32x4 acc[4][4];
#pragma unroll
    for (int m = 0; m < 4; ++m)
#pragma unroll
      for (int nf = 0; nf < 4; ++nf) acc[m][nf] = (f32x4){0.f, 0.f, 0.f, 0.f};

#pragma unroll
    for (int kk = 0; kk < 4; ++kk) {
      short8v xf[4], wf[4];
      int chunk = kk * 4 + kq;
#pragma unroll
      for (int m = 0; m < 4; ++m) {
        int row = wm * 64 + m * 16 + fr;
        xf[m] = *(const short8v*)&Xs[row * 128 + ((chunk ^ (row & 15)) << 3)];
      }
#pragma unroll
      for (int nf = 0; nf < 4; ++nf) {
        int h = wh * 64 + nf * 16 + fr;
        wf[nf] = *(const short8v*)(Wt + (size_t)h * DF + kk * 32 + kq * 8);
      }
#pragma unroll
      for (int m = 0; m < 4; ++m)
#pragma unroll
        for (int nf = 0; nf < 4; ++nf)
          acc[m][nf] = __builtin_amdgcn_mfma_f32_16x16x32_bf16(wf[nf], xf[m], acc[m][nf], 0, 0, 0);
    }

#pragma unroll
    for (int nf = 0; nf < 4; ++nf) {
      float4 b4 = *(const float4*)(bb + wh * 64 + nf * 16 + kq * 4);
#pragma unroll
      for (int m = 0; m < 4; ++m) {
        int node = row0 + wm * 64 + m * 16 + fr;
        if (node < n) {
          f32x4 r = acc[m][nf];
          float v0 = r[0] + b4.x, v1 = r[1] + b4.y, v2 = r[2] + b4.z, v3 = r[3] + b4.w;
          int col = wh * 64 + nf * 16 + kq * 4;
          if (!job && p) {
            *(float4*)(skipf + (size_t)node * DF + col) = make_float4(v0, v1, v2, v3);
          } else {
            short4 s4;
            s4.x = bf16_of(v0); s4.y = bf16_of(v1); s4.z = bf16_of(v2); s4.w = bf16_of(v3);
            if (job) {
              *(short4*)(kvb + (size_t)node * 256 + p * 128 + col) = s4;
            } else {
              *(short4*)(qb + (size_t)node * DF + col) = s4;
            }
          }
        }
      }
    }
  }
}

// ---------------- gq = We @ q via MFMA: [n,128] @ [128,32] ----------------
__global__ __launch_bounds__(256) void gq_mfma_kernel(const short* __restrict__ qb,
                                                      const short* __restrict__ web,
                                                      float* __restrict__ gq, int n) {
  int t = threadIdx.x;
  int lane = t & 63, w = t >> 6;
  int fr = lane & 15, kq = lane >> 4;
  int row0 = blockIdx.x * 128 + w * 32;

  f32x4 acc[2][2];
#pragma unroll
  for (int mm = 0; mm < 2; ++mm)
#pragma unroll
    for (int nf = 0; nf < 2; ++nf) acc[mm][nf] = (f32x4){0.f, 0.f, 0.f, 0.f};

#pragma unroll
  for (int kk = 0; kk < 4; ++kk) {
    short8v af[2], bfr[2];
#pragma unroll
    for (int nf = 0; nf < 2; ++nf) {
      int cc = nf * 16 + fr;
      af[nf] = *(const short8v*)(web + (size_t)cc * DF + kk * 32 + kq * 8);
    }
#pragma unroll
    for (int mm = 0; mm < 2; ++mm) {
      int row = row0 + mm * 16 + fr;
      if (row < n)
        bfr[mm] = *(const short8v*)(qb + (size_t)row * DF + kk * 32 + kq * 8);
      else
        bfr[mm] = (short8v){0, 0, 0, 0, 0, 0, 0, 0};
    }
#pragma unroll
    for (int mm = 0; mm < 2; ++mm)
#pragma unroll
      for (int nf = 0; nf < 2; ++nf)
        acc[mm][nf] = __builtin_amdgcn_mfma_f32_16x16x32_bf16(af[nf], bfr[mm], acc[mm][nf], 0, 0, 0);
  }

#pragma unroll
  for (int mm = 0; mm < 2; ++mm) {
    int node = row0 + mm * 16 + fr;
    if (node < n) {
#pragma unroll
      for (int nf = 0; nf < 2; ++nf) {
        *(f32x4*)(gq + (size_t)node * 32 + nf * 16 + kq * 4) = acc[mm][nf];
      }
    }
  }
}

// ---------------- fused edge attention: 1 node per 16-lane group, 2 edges/iter ----------------
// outputs: tmpob = (agg/ssum + be) bf16 [n,128]; accb = (sum w*ea)/ssum bf16 [n,32]
template <int PERM>
__global__ __launch_bounds__(256) void edge_attn_kernel(
    const short* __restrict__ qb, const short* __restrict__ kvb,
    const float* __restrict__ gq, const float* __restrict__ be,
    const int* __restrict__ src_csr, const int* __restrict__ off,
    const u16* __restrict__ eac, const float* __restrict__ ea, const int* __restrict__ eidc,
    short* __restrict__ tmpob, short* __restrict__ accb, int nd) {
  int lane = threadIdx.x & 63;
  int grp = lane >> 4, sl = lane & 15;
  int node = blockIdx.x * 16 + (threadIdx.x >> 6) * 4 + grp;
  if (node >= nd) return;
  int e0 = off[node], e1 = off[node + 1];

  // lane owns dims sl*8..+8 of its group's node
  ushort8v qu = *(const ushort8v*)((const u16*)qb + (size_t)node * DF + sl * 8);
  float qd[8];
#pragma unroll
  for (int d = 0; d < 8; ++d) qd[d] = f_of_bf16(qu[d]);
  float bed[8];
  {
    float4 b0 = *(const float4*)(be + sl * 8);
    float4 b1 = *(const float4*)(be + sl * 8 + 4);
    bed[0] = b0.x; bed[1] = b0.y; bed[2] = b0.z; bed[3] = b0.w;
    bed[4] = b1.x; bed[5] = b1.y; bed[6] = b1.z; bed[7] = b1.w;
  }
  float pb = 0.f;
#pragma unroll
  for (int d = 0; d < 8; ++d) pb += qd[d] * bed[d];
#pragma unroll
  for (int o = 1; o <= 8; o <<= 1) pb += __shfl_xor(pb, o);

  float2 gq2 = *(const float2*)(gq + (size_t)node * 32 + sl * 2);

  const float scale = 0.08838834764831845f;  // 128^-0.5
  float m = -INFINITY, ssum = 0.f, an0 = 0.f, an1 = 0.f;
  float agg[8];
#pragma unroll
  for (int d = 0; d < 8; ++d) agg[d] = 0.f;

  for (int j0 = e0; j0 < e1; j0 += 2) {
    int j1 = j0 + 1;
    int jc1 = (j1 < e1) ? j1 : e1 - 1;
    int s0 = src_csr[j0], s1 = src_csr[jc1];
    float ea00, ea01, ea10, ea11;
    if (PERM) {
      ushort2 u0 = *(const ushort2*)(eac + (size_t)j0 * EDIM + sl * 2);
      ushort2 u1 = *(const ushort2*)(eac + (size_t)jc1 * EDIM + sl * 2);
      ea00 = f_of_bf16(u0.x); ea01 = f_of_bf16(u0.y);
      ea10 = f_of_bf16(u1.x); ea11 = f_of_bf16(u1.y);
    } else {
      float2 f0 = *(const float2*)(ea + (size_t)eidc[j0] * EDIM + sl * 2);
      float2 f1 = *(const float2*)(ea + (size_t)eidc[jc1] * EDIM + sl * 2);
      ea00 = f0.x; ea01 = f0.y;
      ea10 = f1.x; ea11 = f1.y;
    }
    const u16* kvp0 = (const u16*)kvb + (size_t)s0 * 256 + sl * 8;
    const u16* kvp1 = (const u16*)kvb + (size_t)s1 * 256 + sl * 8;
    ushort8v k0 = *(const ushort8v*)kvp0;
    ushort8v v0 = *(const ushort8v*)(kvp0 + 128);
    ushort8v k1 = *(const ushort8v*)kvp1;
    ushort8v v1 = *(const ushort8v*)(kvp1 + 128);

    float p0 = ea00 * gq2.x + ea01 * gq2.y;
    float p1 = ea10 * gq2.x + ea11 * gq2.y;
#pragma unroll
    for (int d = 0; d < 8; ++d) {
      p0 += qd[d] * f_of_bf16(k0[d]);
      p1 += qd[d] * f_of_bf16(k1[d]);
    }
#pragma unroll
    for (int o = 1; o <= 8; o <<= 1) {
      p0 += __shfl_xor(p0, o);
      p1 += __shfl_xor(p1, o);
    }
    float a0 = (p0 + pb) * scale;
    float a1 = (j1 < e1) ? (p1 + pb) * scale : -INFINITY;
    float mn = fmaxf(m, fmaxf(a0, a1));
    if (mn > m) {  // group-uniform
      float f = __expf(m - mn);
      ssum *= f; an0 *= f; an1 *= f;
#pragma unroll
      for (int d = 0; d < 8; ++d) agg[d] *= f;
      m = mn;
    }
    float w0 = __expf(a0 - m);
    float w1 = __expf(a1 - m);  // 0 for invalid (a1 = -inf)
    ssum += w0 + w1;
    an0 += w0 * ea00 + w1 * ea10;
    an1 += w0 * ea01 + w1 * ea11;
#pragma unroll
    for (int d = 0; d < 8; ++d) agg[d] += w0 * f_of_bf16(v0[d]) + w1 * f_of_bf16(v1[d]);
  }

  float inv = (ssum > 0.f) ? 1.f / ssum : 0.f;
  short2 a2;
  a2.x = bf16_of(an0 * inv);
  a2.y = bf16_of(an1 * inv);
  *(short2*)(accb + (size_t)node * 32 + sl * 2) = a2;
  short8v t8;
#pragma unroll
  for (int d = 0; d < 8; ++d)
    t8[d] = bf16_of((ssum > 0.f) ? agg[d] * inv + bed[d] : 0.f);
  *(short8v*)(tmpob + (size_t)node * DF + sl * 8) = t8;
}

// ---------------- post-pass: out = [relu](skip + tmpob + accn @ We) ----------------
__global__ __launch_bounds__(256) void accw_kernel(
    const float* __restrict__ skipf, const short* __restrict__ tmpob,
    const short* __restrict__ accb, const short* __restrict__ webT,
    float* __restrict__ outf, short* __restrict__ outb, int n, int relu) {
  int t = threadIdx.x;
  int lane = t & 63, w = t >> 6;
  int fr = lane & 15, kq = lane >> 4;
  int row0 = blockIdx.x * 128 + w * 32;

  short8v af[8];
#pragma unroll
  for (int nf = 0; nf < 8; ++nf)
    af[nf] = *(const short8v*)(webT + (size_t)(nf * 16 + fr) * 32 + kq * 8);

#pragma unroll
  for (int mm = 0; mm < 2; ++mm) {
    int row = row0 + mm * 16 + fr;
    short8v b;
    if (row < n)
      b = *(const short8v*)(accb + (size_t)row * 32 + kq * 8);
    else
      b = (short8v){0, 0, 0, 0, 0, 0, 0, 0};
#pragma unroll
    for (int nf = 0; nf < 8; ++nf) {
      f32x4 acc = (f32x4){0.f, 0.f, 0.f, 0.f};
      acc = __builtin_amdgcn_mfma_f32_16x16x32_bf16(af[nf], b, acc, 0, 0, 0);
      if (row < n) {
        size_t o = (size_t)row * DF + nf * 16 + kq * 4;
        float4 skp = *(const float4*)(skipf + o);
        ushort4 tb = *(const ushort4*)((const u16*)tmpob + o);
        float r0 = skp.x + f_of_bf16(tb.x) + acc[0];
        float r1 = skp.y + f_of_bf16(tb.y) + acc[1];
        float r2 = skp.z + f_of_bf16(tb.z) + acc[2];
        float r3 = skp.w + f_of_bf16(tb.w) + acc[3];
        if (relu) {
          r0 = fmaxf(r0, 0.f); r1 = fmaxf(r1, 0.f);
          r2 = fmaxf(r2, 0.f); r3 = fmaxf(r3, 0.f);
        }
        if (outf) *(float4*)(outf + o) = make_float4(r0, r1, r2, r3);
        if (outb) {
          short4 s4;
          s4.x = bf16_of(r0); s4.y = bf16_of(r1); s4.z = bf16_of(r2); s4.w = bf16_of(r3);
          *(short4*)(outb + o) = s4;
        }
      }
    }
  }
}

// ---------------- launch ----------------

extern "C" void kernel_launch(void* const* d_in, const int* in_sizes, int n_in,
                              void* d_out, int out_size, void* d_ws, size_t ws_size,
                              hipStream_t stream) {
  const float* x_user = (const float*)d_in[0];
  const float* x_item = (const float*)d_in[1];
  const float* ea_ui = (const float*)d_in[2];
  const float* ea_iu = (const float*)d_in[3];
  const float* Wq = (const float*)d_in[4];
  const float* bq = (const float*)d_in[5];
  const float* Wk = (const float*)d_in[6];
  const float* bk = (const float*)d_in[7];
  const float* Wv = (const float*)d_in[8];
  const float* bv = (const float*)d_in[9];
  const float* We = (const float*)d_in[10];
  const float* be = (const float*)d_in[11];
  const float* Ws = (const float*)d_in[12];
  const float* bs = (const float*)d_in[13];
  const int* ei_ui = (const int*)d_in[14];
  const int* ei_iu = (const int*)d_in[15];
  float* out = (float*)d_out;

  char* wp = (char*)d_ws;
  size_t used = 0;
  auto alloc = [&](size_t bytes) {
    void* p = (void*)(wp + used);
    used += (bytes + 255) & ~(size_t)255;
    return p;
  };
  const size_t NB = (size_t)NNODE * DF;
  short* xub = (short*)alloc(NB * 2);
  short* xib = (short*)alloc(NB * 2);
  short* xu1b = (short*)alloc(NB * 2);
  short* xi1b = (short*)alloc(NB * 2);
  short* qb = (short*)alloc(NB * 2);
  short* kvb = (short*)alloc(NB * 4);   // interleaved k|v rows of 256
  float* skipf = (float*)alloc(NB * 4);
  short* tmpob = (short*)alloc(NB * 2);
  float* gqbuf = (float*)alloc((size_t)NNODE * 32 * 4);
  short* accb = (short*)alloc((size_t)NNODE * 32 * 2);
  short* wt = (short*)alloc((size_t)4 * 4 * 16384 * 2);
  short* web = (short*)alloc((size_t)4 * 4096 * 2);
  short* webT = (short*)alloc((size_t)4 * 4096 * 2);
  int* cnt = (int*)alloc((size_t)2 * (NNODE + 1) * 4);
  int* off = (int*)alloc((size_t)2 * (NNODE + 1) * 4);
  int* src_ui = (int*)alloc((size_t)NEDGE * 4);
  int* src_iu = (int*)alloc((size_t)NEDGE * 4);
  int* eid_ui = (int*)alloc((size_t)NEDGE * 4);
  int* eid_iu = (int*)alloc((size_t)NEDGE * 4);
  size_t eac_bytes = (size_t)NEDGE * EDIM * 2;
  bool use_eac = (used + 2 * (eac_bytes + 256)) <= ws_size;
  u16* eac_ui = use_eac ? (u16*)alloc(eac_bytes) : nullptr;
  u16* eac_iu = use_eac ? (u16*)alloc(eac_bytes) : nullptr;

  const int PB = (NNODE + 127) / 128;  // 782
  int* off_ui = off;
  int* off_iu = off + (NNODE + 1);

  cast2_kernel<<<(int)(2 * NB / 4 + 255) / 256, 256, 0, stream>>>(
      x_user, x_item, xub, xib, (int)(NB / 4));
  transW_kernel<<<(4 * 4 * 16384 + 2 * 4 * 4096 + 255) / 256, 256, 0, stream>>>(
      Wq, Wk, Wv, Ws, We, wt, web, webT);

  hipMemsetAsync(cnt, 0, 2 * (NNODE + 1) * sizeof(int), stream);
  hist2_kernel<<<(2 * NEDGE + 255) / 256, 256, 0, stream>>>(
      ei_ui + NEDGE, ei_iu + NEDGE, cnt, NEDGE);
  scan_kernel<<<2, 1024, 0, stream>>>(cnt, off, NNODE);
  hipMemcpyAsync(cnt, off, 2 * (NNODE + 1) * sizeof(int), hipMemcpyDeviceToDevice, stream);
  scatter2_kernel<<<(2 * NEDGE + 255) / 256, 256, 0, stream>>>(
      ei_ui, ei_ui + NEDGE, ea_ui, ei_iu, ei_iu + NEDGE, ea_iu, cnt,
      src_ui, src_iu, use_eac ? nullptr : eid_ui, use_eac ? nullptr : eid_iu,
      eac_ui, eac_iu, NEDGE);

  auto run_conv = [&](const short* xsb, const short* xdb, int wsel, const u16* eac_t,
                      const float* ea_t, const int* eid_t, const int* src_t, const int* off_t,
                      float* outfp, short* outbp, int relu) {
    dim3 g(PB, 2);
    proj_kernel<<<g, 256, 0, stream>>>(
        xdb, xsb, NNODE,
        wt + (size_t)0 * 65536 + (size_t)wsel * 16384, bq + (size_t)wsel * DF, qb,
        wt + (size_t)3 * 65536 + (size_t)wsel * 16384, bs + (size_t)wsel * DF, skipf,
        wt + (size_t)1 * 65536 + (size_t)wsel * 16384, bk + (size_t)wsel * DF,
        wt + (size_t)2 * 65536 + (size_t)wsel * 16384, bv + (size_t)wsel * DF, kvb);
    gq_mfma_kernel<<<PB, 256, 0, stream>>>(qb, web + (size_t)wsel * 4096, gqbuf, NNODE);
    if (use_eac)
      edge_attn_kernel<1><<<(NNODE + 15) / 16, 256, 0, stream>>>(
          qb, kvb, gqbuf, be + (size_t)wsel * DF,
          src_t, off_t, eac_t, nullptr, nullptr, tmpob, accb, NNODE);
    else
      edge_attn_kernel<0><<<(NNODE + 15) / 16, 256, 0, stream>>>(
          qb, kvb, gqbuf, be + (size_t)wsel * DF,
          src_t, off_t, nullptr, ea_t, eid_t, tmpob, accb, NNODE);
    accw_kernel<<<PB, 256, 0, stream>>>(
        skipf, tmpob, accb, webT + (size_t)wsel * 4096, outfp, outbp, NNODE, relu);
  };

  // layer 0 (ReLU): outputs bf16 only
  run_conv(xub, xib, 0, eac_ui, ea_ui, eid_ui, src_ui, off_ui, nullptr, xi1b, 1);
  run_conv(xib, xub, 1, eac_iu, ea_iu, eid_iu, src_iu, off_iu, nullptr, xu1b, 1);
  // layer 1 (no ReLU): f32 into d_out = [x_user | x_item]
  run_conv(xu1b, xi1b, 2, eac_ui, ea_ui, eid_ui, src_ui, off_ui, out + NB, nullptr, 0);
  run_conv(xi1b, xu1b, 3, eac_iu, ea_iu, eid_iu, src_iu, off_iu, out, nullptr, 0);
}